// Round 9
// baseline (710.048 us; speedup 1.0000x reference)
//
#include <hip/hip_runtime.h>

typedef unsigned short u16;
typedef unsigned int u32;
typedef __attribute__((ext_vector_type(4))) float f32x4;
typedef __attribute__((ext_vector_type(8))) short short8;
typedef __attribute__((ext_vector_type(4))) unsigned short u16x4;

#define BARR __builtin_amdgcn_s_barrier()
#define VM4  asm volatile("s_waitcnt vmcnt(4)" ::: "memory")
#define VM0  asm volatile("s_waitcnt vmcnt(0)" ::: "memory")

// ---------- helpers ----------
__device__ __forceinline__ u16 f2b(float f){
  u32 u = __float_as_uint(f);
  u = (u + 0x7FFFu + ((u >> 16) & 1u)) >> 16;   // RNE
  return (u16)u;
}
__device__ __forceinline__ float b2f(u16 h){ return __uint_as_float(((u32)h) << 16); }

__device__ __forceinline__ void gload16(const void* g, void* l){
  __builtin_amdgcn_global_load_lds((__attribute__((address_space(1))) void*)(g),
                                   (__attribute__((address_space(3))) void*)(l), 16, 0, 0);
}

// ---------- W f32 [R][C] -> bf16 transposed [C][R], per expert (vectorized) ----------
__global__ __launch_bounds__(256) void transpose_cvt_kernel(const float* __restrict__ src,
                                                            u16* __restrict__ dst,
                                                            int R, int C){
  __shared__ float t[64][65];
  int e = blockIdx.z;
  size_t eo = (size_t)R * C * e;
  int c0 = blockIdx.x * 64, r0 = blockIdx.y * 64;
  int tid = threadIdx.x;
  int lr = tid >> 4, lc4 = (tid & 15) * 4;
  #pragma unroll
  for (int i = 0; i < 4; i++){
    int r = lr + i * 16;
    float4 v = *(const float4*)&src[eo + (size_t)(r0 + r) * C + c0 + lc4];
    t[r][lc4] = v.x; t[r][lc4 + 1] = v.y; t[r][lc4 + 2] = v.z; t[r][lc4 + 3] = v.w;
  }
  __syncthreads();
  #pragma unroll
  for (int i = 0; i < 4; i++){
    int c = lr + i * 16;
    u16x4 o = { f2b(t[lc4][c]), f2b(t[lc4 + 1][c]), f2b(t[lc4 + 2][c]), f2b(t[lc4 + 3][c]) };
    *(u16x4*)&dst[eo + (size_t)(c0 + c) * R + r0 + lc4] = o;
  }
}

// ---------- gating v2 (R7, proven): register weights, batched epilogue ----------
__global__ __launch_bounds__(256) void gating_kernel(const float* __restrict__ x,
                                                     const float* __restrict__ nz,
                                                     const float* __restrict__ wg,
                                                     const float* __restrict__ wn,
                                                     int* __restrict__ counts,
                                                     int4* __restrict__ rowinfo,
                                                     float* __restrict__ loadrow,
                                                     u16* __restrict__ xb){
  __shared__ float wpart[16][4][17];
  int tid = threadIdx.x, w = tid >> 6, lane = tid & 63;
  int d0 = w * 256 + lane * 4;
  float4 wgA[4], wgB[4], wnA[4], wnB[4];
  #pragma unroll
  for (int k = 0; k < 4; k++){
    wgA[k] = *(const float4*)&wg[(d0 + k) * 8];
    wgB[k] = *(const float4*)&wg[(d0 + k) * 8 + 4];
    wnA[k] = *(const float4*)&wn[(d0 + k) * 8];
    wnB[k] = *(const float4*)&wn[(d0 + k) * 8 + 4];
  }
  int rbase = blockIdx.x * 16;
  for (int r = 0; r < 16; r++){
    int row = rbase + r;
    float4 xv = *(const float4*)&x[(size_t)row * 1024 + d0];
    u16x4 xo = { f2b(xv.x), f2b(xv.y), f2b(xv.z), f2b(xv.w) };
    *(u16x4*)&xb[(size_t)row * 1024 + d0] = xo;
    float ag[8], an[8];
    #pragma unroll
    for (int e = 0; e < 8; e++){ ag[e] = 0.f; an[e] = 0.f; }
    float xk[4] = { xv.x, xv.y, xv.z, xv.w };
    #pragma unroll
    for (int k = 0; k < 4; k++){
      ag[0] = fmaf(xk[k], wgA[k].x, ag[0]); ag[1] = fmaf(xk[k], wgA[k].y, ag[1]);
      ag[2] = fmaf(xk[k], wgA[k].z, ag[2]); ag[3] = fmaf(xk[k], wgA[k].w, ag[3]);
      ag[4] = fmaf(xk[k], wgB[k].x, ag[4]); ag[5] = fmaf(xk[k], wgB[k].y, ag[5]);
      ag[6] = fmaf(xk[k], wgB[k].z, ag[6]); ag[7] = fmaf(xk[k], wgB[k].w, ag[7]);
      an[0] = fmaf(xk[k], wnA[k].x, an[0]); an[1] = fmaf(xk[k], wnA[k].y, an[1]);
      an[2] = fmaf(xk[k], wnA[k].z, an[2]); an[3] = fmaf(xk[k], wnA[k].w, an[3]);
      an[4] = fmaf(xk[k], wnB[k].x, an[4]); an[5] = fmaf(xk[k], wnB[k].y, an[5]);
      an[6] = fmaf(xk[k], wnB[k].z, an[6]); an[7] = fmaf(xk[k], wnB[k].w, an[7]);
    }
    #pragma unroll
    for (int off = 32; off >= 1; off >>= 1){
      #pragma unroll
      for (int e = 0; e < 8; e++){
        ag[e] += __shfl_xor(ag[e], off, 64);
        an[e] += __shfl_xor(an[e], off, 64);
      }
    }
    if (lane == 0){
      #pragma unroll
      for (int e = 0; e < 8; e++){
        wpart[r][w][e] = ag[e];
        wpart[r][w][8 + e] = an[e];
      }
    }
  }
  __syncthreads();
  if (tid < 16){
    int r = tid, row = rbase + r;
    float cg[16];
    #pragma unroll
    for (int v = 0; v < 16; v++)
      cg[v] = wpart[r][0][v] + wpart[r][1][v] + wpart[r][2][v] + wpart[r][3][v];
    float clean[8], sd[8], noisy[8];
    #pragma unroll
    for (int e = 0; e < 8; e++){
      clean[e] = cg[e];
      float v = cg[8 + e];
      float sp = fmaxf(v, 0.f) + log1pf(expf(-fabsf(v)));
      sd[e] = sp + 0.01f;
      noisy[e] = clean[e] + nz[row * 8 + e] * sd[e];
    }
    int i0 = 0, i1 = -1;
    float b0 = -3.4e38f, b1v = -3.4e38f, b2v = -3.4e38f;
    #pragma unroll
    for (int j = 0; j < 8; j++){
      float t = noisy[j];
      if (t > b0){ b2v = b1v; b1v = b0; i1 = i0; b0 = t; i0 = j; }
      else if (t > b1v){ b2v = b1v; b1v = t; i1 = j; }
      else if (t > b2v){ b2v = t; }
    }
    float eg = expf(b1v - b0);
    float g0 = 1.f / (1.f + eg), g1 = eg / (1.f + eg);
    rowinfo[row] = make_int4(i0, i1, __float_as_int(g0), __float_as_int(g1));
    atomicAdd(&counts[i0], 1);
    atomicAdd(&counts[i1], 1);
    float thr_in = b2v, thr_out = b1v;
    #pragma unroll
    for (int e = 0; e < 8; e++){
      bool isin = noisy[e] > thr_in;
      float thr = isin ? thr_in : thr_out;
      float z = (clean[e] - thr) / sd[e];
      loadrow[row * 8 + e] = 0.5f * (1.f + erff(z * 0.70710678118654752f));
    }
  }
}

// ---------- fill dispatch lists (scan fused: block-local prefix, block 0 publishes) ----------
__global__ __launch_bounds__(256) void fill_kernel(const int* __restrict__ counts,
                                                   const int4* __restrict__ rowinfo,
                                                   int* __restrict__ offs,
                                                   int* __restrict__ cnt2,
                                                   int* __restrict__ tok,
                                                   int* __restrict__ slot_of,
                                                   int* __restrict__ btab){
  __shared__ int loff[8];
  if (threadIdx.x == 0){
    int s = 0;
    for (int e = 0; e < 8; e++){ loff[e] = s; s += counts[e]; }
    if (blockIdx.x == 0){
      int nb = 0;
      for (int e = 0; e < 8; e++){
        offs[e] = loff[e];
        int nbe = (counts[e] + 255) >> 8;
        for (int t = 0; t < nbe; t++) btab[nb++] = (e << 16) | t;
      }
      offs[15] = nb;
    }
  }
  __syncthreads();
  int r = blockIdx.x * 256 + threadIdx.x;
  int4 ri = rowinfo[r];
  int p0 = atomicAdd(&cnt2[ri.x], 1);
  int s0 = loff[ri.x] + p0;
  tok[s0] = r; slot_of[2 * r] = s0;
  int p1 = atomicAdd(&cnt2[ri.y], 1);
  int s1 = loff[ri.y] + p1;
  tok[s1] = r; slot_of[2 * r + 1] = s1;
}

// ---------- grouped GEMM, 256x256, 8-phase counted-vmcnt + early-read overlap ----------
// Schedule identical to R6-R8 (ledger-audited, peeled last iter with VM0).
// NEW (R9): epilogue stages the C tile through the (drained) 128KB LDS with a
// granule-XOR swizzle, then stores 16B short8 chunks, 32 threads/row -> 512B
// contiguous segments (was 2B/lane u16 stores = 32B segments, 1.5x write amp).
template<int KDIM, bool GATHER, bool RELU, bool PSPLIT>
__global__ __launch_bounds__(512, 1) void ffn8_kernel(
    const u16* __restrict__ Ag, const u16* __restrict__ Bt,
    const float* __restrict__ bias, u16* __restrict__ outp,
    const int* __restrict__ counts, const int* __restrict__ offs,
    const int* __restrict__ btab, const int* __restrict__ tok,
    int nc, int klen, int ostr, size_t pstride)
{
  __shared__ u16 SMEM[65536];                     // As(64K) + Bs(64K); reused for C staging
  u16 (*As)[2][8192] = (u16(*)[2][8192])SMEM;
  u16 (*Bs)[2][8192] = (u16(*)[2][8192])(SMEM + 32768);

  int gx = gridDim.x;
  int lin = blockIdx.y * gx + blockIdx.x;
  int total = gx * gridDim.y, chunk = total >> 3;
  int swz = (lin & 7) * chunk + (lin >> 3);       // bijective: total % 8 == 0
  int bx = swz % gx, tq = swz / gx;
  int nblk = offs[15];
  if (bx >= nblk) return;
  int kh = tq / nc;
  int tn = tq - kh * nc;
  int kbase = kh * klen;
  int niter = klen >> 7;                          // klen/128 (2 tiles/iter)
  int et = btab[bx]; int e = et >> 16, tm = et & 0xffff;
  int cnt = counts[e], off_e = offs[e];

  int tid = threadIdx.x, lane = tid & 63;
  int wid = tid >> 6, wm = wid >> 2, wn = wid & 3;

  // staging source byte offsets (source pre-swizzled; LDS dest linear — rule #21)
  int rl0 = tid >> 3, c8 = tid & 7;
  const char* Abase = (const char*)Ag + (size_t)kbase * 2;
  const char* Bbase = (const char*)(Bt + (size_t)e * 4194304) + (size_t)kbase * 2;
  u32 aoff[4], boff[4];
  #pragma unroll
  for (int h = 0; h < 2; h++)
    #pragma unroll
    for (int r = 0; r < 2; r++){
      int rl = h * 128 + r * 64 + rl0;
      int c8s = c8 ^ (rl & 7);
      int rr = tm * 256 + rl;
      int rc = (rr < cnt) ? rr : (cnt - 1);
      size_t arow = GATHER ? (size_t)tok[off_e + rc] : (size_t)(off_e + rc);
      aoff[h * 2 + r] = (u32)(arow * (KDIM * 2) + c8s * 16);
      boff[h * 2 + r] = (u32)((size_t)(tn * 256 + rl) * (KDIM * 2) + c8s * 16);
    }
  int ldst = (tid & ~63) * 8;   // wave-uniform linear LDS dest (elements)

  auto stA = [&](int b, int h, int t){
    const char* s = Abase + (size_t)t * 128;
    gload16(s + aoff[h * 2 + 0], &As[b][h][ldst]);
    gload16(s + aoff[h * 2 + 1], &As[b][h][4096 + ldst]);
  };
  auto stB = [&](int b, int h, int t){
    const char* s = Bbase + (size_t)t * 128;
    gload16(s + boff[h * 2 + 0], &Bs[b][h][ldst]);
    gload16(s + boff[h * 2 + 1], &Bs[b][h][4096 + ldst]);
  };

  int lm = lane & 15, lkb = (lane >> 4) * 8;
  short8 Ar[4][2], Br[2][2][2];
  auto ldA = [&](int b, int rh){
    #pragma unroll
    for (int ii = 0; ii < 4; ii++){
      int rl = rh * 64 + ii * 16 + lm;
      #pragma unroll
      for (int ks = 0; ks < 2; ks++){
        int idx = (rl * 64 + ks * 32 + lkb) ^ ((rl & 7) << 3);
        Ar[ii][ks] = *(const short8*)&As[b][wm][idx];
      }
    }
  };
  auto ldB = [&](int b, int ch){
    #pragma unroll
    for (int jj = 0; jj < 2; jj++){
      int rb = wn * 64 + ch * 32 + jj * 16 + lm;
      int hB = rb >> 7, rl = rb & 127;
      #pragma unroll
      for (int ks = 0; ks < 2; ks++){
        int idx = (rl * 64 + ks * 32 + lkb) ^ ((rl & 7) << 3);
        Br[ch][jj][ks] = *(const short8*)&Bs[b][hB][idx];
      }
    }
  };

  f32x4 acc[8][4];
  #pragma unroll
  for (int i = 0; i < 8; i++)
    #pragma unroll
    for (int j = 0; j < 4; j++) acc[i][j] = (f32x4){0.f, 0.f, 0.f, 0.f};

  auto mfmaQ = [&](int rh, int ch){
    __builtin_amdgcn_s_setprio(1);
    #pragma unroll
    for (int ks = 0; ks < 2; ks++)
      #pragma unroll
      for (int ii = 0; ii < 4; ii++)
        #pragma unroll
        for (int jj = 0; jj < 2; jj++)
          acc[rh * 4 + ii][ch * 2 + jj] = __builtin_amdgcn_mfma_f32_16x16x32_bf16(
              Ar[ii][ks], Br[ch][jj][ks], acc[rh * 4 + ii][ch * 2 + jj], 0, 0, 0);
    __builtin_amdgcn_s_setprio(0);
  };

  // prologue: t0 all 4 halves -> buf0; t1's B-h0, A-h0 -> buf1
  stA(0, 0, 0); stA(0, 1, 0); stB(0, 0, 0); stB(0, 1, 0);
  stB(1, 0, 1); stA(1, 0, 1);
  VM4; BARR;

  for (int j = 0; j < niter - 1; ++j){
    int t1 = 2 * j + 1, t2 = 2 * j + 2, t3 = 2 * j + 3;
    // P1
    ldA(0, 0); ldB(0, 0);
    stA(1, 1, t1);
    BARR; mfmaQ(0, 0); ldB(0, 1); BARR;
    // P2
    stB(1, 1, t1);
    BARR; mfmaQ(0, 1); ldA(0, 1); BARR;
    // P3
    stB(0, 0, t2);
    BARR; mfmaQ(1, 1); BARR;
    // P4 (Br[0] regs still hold buf0 ch0)
    stA(0, 0, t2);
    BARR; mfmaQ(1, 0); VM4; BARR;
    // P5
    ldA(1, 0); ldB(1, 0);
    stA(0, 1, t2);
    BARR; mfmaQ(0, 0); ldB(1, 1); BARR;
    // P6
    stB(0, 1, t2);
    BARR; mfmaQ(0, 1); ldA(1, 1); BARR;
    // P7
    stB(1, 0, t3);
    BARR; mfmaQ(1, 1); BARR;
    // P8
    stA(1, 0, t3);
    BARR; mfmaQ(1, 0); VM4; BARR;
  }

  { // peeled last iteration: only P1/P2 stage (complete tile NT-1), full drain at P4
    int t1 = (klen >> 6) - 1;
    ldA(0, 0); ldB(0, 0);
    stA(1, 1, t1);
    BARR; mfmaQ(0, 0); ldB(0, 1); BARR;
    stB(1, 1, t1);
    BARR; mfmaQ(0, 1); ldA(0, 1); BARR;
    BARR; mfmaQ(1, 1); BARR;
    mfmaQ(1, 0); VM0; BARR;
    ldA(1, 0); ldB(1, 0);
    BARR; mfmaQ(0, 0); ldB(1, 1); BARR;
    BARR; mfmaQ(0, 1); ldA(1, 1); BARR;
    BARR; mfmaQ(1, 1); BARR;
    mfmaQ(1, 0);
  }

  // ---------- epilogue: LDS-staged coalesced C write ----------
  // All gload_lds drained (VM0 in peel, no stages after) -> no WAR on SMEM.
  BARR;   // all waves done reading As/Bs
  u16* po = outp + (PSPLIT ? (size_t)kh * pstride : 0);
  int lr4 = (lane >> 4) * 4;
  #pragma unroll
  for (int i = 0; i < 8; i++){
    int rl = wm * 128 + i * 16 + lr4;
    #pragma unroll
    for (int jj = 0; jj < 4; jj++){
      int col = wn * 64 + jj * 16 + lm;          // tile-local col 0..255
      float bv = PSPLIT ? 0.f : bias[e * ostr + tn * 256 + col];
      #pragma unroll
      for (int q = 0; q < 4; q++){
        int row = rl + q;
        float v = acc[i][jj][q] + bv;
        if (RELU) v = fmaxf(v, 0.f);
        int g = (col >> 3) ^ (row & 7);          // granule swizzle (16B granules)
        SMEM[row * 256 + (g << 3) + (col & 7)] = f2b(v);
      }
    }
  }
  BARR;
  int srow = tid >> 5;                           // 0..15
  int scg  = tid & 31;                           // col granule 0..31
  #pragma unroll
  for (int p = 0; p < 16; p++){
    int row = p * 16 + srow;
    int g = scg ^ (row & 7);
    short8 vv = *(const short8*)&SMEM[row * 256 + (g << 3)];
    int grow = tm * 256 + row;
    if (grow < cnt){
      *(short8*)(po + (size_t)(off_e + grow) * ostr + tn * 256 + (scg << 3)) = vv;
    }
  }
}

// ---------- combine: 4 rows/block, wave-per-row, 512B read segments ----------
__global__ __launch_bounds__(256) void combine_kernel(const u16* __restrict__ pb,
                                                      const float* __restrict__ b2,
                                                      const int4* __restrict__ rowinfo,
                                                      const int* __restrict__ slot_of,
                                                      float* __restrict__ y){
  const size_t PS = (size_t)16384 * 1024;
  int w = threadIdx.x >> 6, lane = threadIdx.x & 63;
  int row = blockIdx.x * 4 + w;
  int4 ri = rowinfo[row];
  float g0 = __int_as_float(ri.z), g1 = __int_as_float(ri.w);
  int s0 = slot_of[2 * row], s1 = slot_of[2 * row + 1];
  const u16* pa = pb + ((size_t)s0 << 10);
  const u16* pbb = pb + ((size_t)s1 << 10);
  #pragma unroll
  for (int k = 0; k < 4; k++){
    int c4 = k * 256 + lane * 4;
    float4 sum0 = *(const float4*)&b2[(ri.x << 10) + c4];
    float4 sum1 = *(const float4*)&b2[(ri.y << 10) + c4];
    #pragma unroll
    for (int kh = 0; kh < 4; kh++){
      u16x4 a = *(const u16x4*)&pa[kh * PS + c4];
      u16x4 b = *(const u16x4*)&pbb[kh * PS + c4];
      sum0.x += b2f(a.x); sum0.y += b2f(a.y); sum0.z += b2f(a.z); sum0.w += b2f(a.w);
      sum1.x += b2f(b.x); sum1.y += b2f(b.y); sum1.z += b2f(b.z); sum1.w += b2f(b.w);
    }
    float4 o;
    o.x = g0 * sum0.x + g1 * sum1.x;
    o.y = g0 * sum0.y + g1 * sum1.y;
    o.z = g0 * sum0.z + g1 * sum1.z;
    o.w = g0 * sum0.w + g1 * sum1.w;
    *(float4*)&y[(size_t)row * 1024 + c4] = o;
  }
}

// ---------- loss stage 1: 32 blocks x 256 rows -> partials[32][16] ----------
__global__ __launch_bounds__(256) void loss1_kernel(const int4* __restrict__ rowinfo,
                                                    const float* __restrict__ loadrow,
                                                    float* __restrict__ partials){
  __shared__ float part[16][256];
  int tid = threadIdx.x;
  int r = blockIdx.x * 256 + tid;
  int4 ri = rowinfo[r];
  float g0 = __int_as_float(ri.z), g1 = __int_as_float(ri.w);
  f32x4 l0 = *(const f32x4*)&loadrow[r * 8];
  f32x4 l1 = *(const f32x4*)&loadrow[r * 8 + 4];
  #pragma unroll
  for (int e = 0; e < 8; e++){
    part[e][tid] = ((ri.x == e) ? g0 : 0.f) + ((ri.y == e) ? g1 : 0.f);
    part[8 + e][tid] = (e < 4) ? l0[e & 3] : l1[e & 3];
  }
  __syncthreads();
  #pragma unroll
  for (int s = 128; s >= 1; s >>= 1){
    if (tid < s){
      #pragma unroll
      for (int e = 0; e < 16; e++) part[e][tid] += part[e][tid + s];
    }
    __syncthreads();
  }
  if (tid < 16) partials[blockIdx.x * 16 + tid] = part[tid][0];
}

// ---------- loss stage 2 ----------
__global__ __launch_bounds__(64) void loss2_kernel(const float* __restrict__ partials,
                                                   float* __restrict__ out_loss){
  __shared__ float tot[16];
  int tid = threadIdx.x;
  if (tid < 16){
    float s = 0.f;
    for (int b = 0; b < 32; b++) s += partials[b * 16 + tid];
    tot[tid] = s;
  }
  __syncthreads();
  if (tid == 0){
    float mi = 0.f, ml = 0.f;
    for (int e = 0; e < 8; e++){ mi += tot[e]; ml += tot[8 + e]; }
    mi *= 0.125f; ml *= 0.125f;
    float vi = 0.f, vl = 0.f;
    for (int e = 0; e < 8; e++){
      float di = tot[e] - mi; vi += di * di;
      float dl = tot[8 + e] - ml; vl += dl * dl;
    }
    vi /= 7.f; vl /= 7.f;
    float cvi = vi / (mi * mi + 1e-10f);
    float cvl = vl / (ml * ml + 1e-10f);
    out_loss[0] = 0.01f * (cvi + cvl);
  }
}

// ---------- launch ----------
extern "C" void kernel_launch(void* const* d_in, const int* in_sizes, int n_in,
                              void* d_out, int out_size, void* d_ws, size_t ws_size,
                              hipStream_t stream){
  const float* x  = (const float*)d_in[0];
  const float* nz = (const float*)d_in[1];
  const float* wg = (const float*)d_in[2];
  const float* wn = (const float*)d_in[3];
  const float* W1 = (const float*)d_in[4];
  const float* b1 = (const float*)d_in[5];
  const float* W2 = (const float*)d_in[6];
  const float* b2 = (const float*)d_in[7];
  float* y = (float*)d_out;
  float* loss = y + (size_t)8192 * 1024;

  char* ws = (char*)d_ws;
  size_t o = 0;
  auto alloc = [&](size_t bytes){ size_t r = o; o += (bytes + 255) & ~(size_t)255; return r; };
  int*  counts  = (int*)(ws + alloc(64));
  int*  cnt2    = (int*)(ws + alloc(64));
  int*  offs    = (int*)(ws + alloc(64));
  int*  btab    = (int*)(ws + alloc(1024));
  int4* rowinfo = (int4*)(ws + alloc((size_t)8192 * 16));
  int*  slot_of = (int*)(ws + alloc((size_t)16384 * 4));
  int*  tok     = (int*)(ws + alloc((size_t)16384 * 4));
  float* loadrow = (float*)(ws + alloc((size_t)8192 * 8 * 4));
  float* partials = (float*)(ws + alloc(32 * 16 * 4));
  u16*  xb      = (u16*)(ws + alloc((size_t)8192 * 1024 * 2));
  u16*  w1t     = (u16*)(ws + alloc((size_t)8 * 1024 * 4096 * 2));
  u16*  w2t     = (u16*)(ws + alloc((size_t)8 * 1024 * 4096 * 2));
  u16*  h_buf   = (u16*)(ws + alloc((size_t)16384 * 4096 * 2));
  u16*  pbuf    = (u16*)(ws + alloc((size_t)4 * 16384 * 1024 * 2));
  if (o > ws_size) return;

  hipMemsetAsync(ws, 0, 768, stream);  // counts, cnt2, offs

  gating_kernel<<<512, 256, 0, stream>>>(x, nz, wg, wn, counts, rowinfo, loadrow, xb);
  transpose_cvt_kernel<<<dim3(64, 16, 8), 256, 0, stream>>>(W1, w1t, 1024, 4096);
  transpose_cvt_kernel<<<dim3(16, 64, 8), 256, 0, stream>>>(W2, w2t, 4096, 1024);
  fill_kernel<<<32, 256, 0, stream>>>(counts, rowinfo, offs, cnt2, tok, slot_of, btab);
  // ffn1: K=1024, bf16 out with bias+relu (nc=16 col tiles, kh always 0)
  ffn8_kernel<1024, true, true, false><<<dim3(72, 16), 512, 0, stream>>>(
      xb, w1t, b1, h_buf, counts, offs, btab, tok, 16, 1024, 4096, 0);
  // ffn2: K split 4x1024 in ONE dispatch (nc=4 col tiles x 4 kh), bf16 partials
  ffn8_kernel<4096, false, false, true><<<dim3(72, 16), 512, 0, stream>>>(
      h_buf, w2t, nullptr, pbuf, counts, offs, btab, tok, 4, 1024, 1024,
      (size_t)16384 * 1024);
  combine_kernel<<<2048, 256, 0, stream>>>(pbuf, b2, rowinfo, slot_of, y);
  loss1_kernel<<<32, 256, 0, stream>>>(rowinfo, loadrow, partials);
  loss2_kernel<<<1, 64, 0, stream>>>(partials, loss);
}

// Round 10
// 683.635 us; speedup vs baseline: 1.0386x; 1.0386x over previous
//
#include <hip/hip_runtime.h>

typedef unsigned short u16;
typedef unsigned int u32;
typedef __attribute__((ext_vector_type(4))) float f32x4;
typedef __attribute__((ext_vector_type(8))) short short8;
typedef __attribute__((ext_vector_type(4))) unsigned short u16x4;

#define BARR __builtin_amdgcn_s_barrier()
#define VM4  asm volatile("s_waitcnt vmcnt(4)" ::: "memory")
#define VM0  asm volatile("s_waitcnt vmcnt(0)" ::: "memory")

// ---------- helpers ----------
__device__ __forceinline__ u16 f2b(float f){
  u32 u = __float_as_uint(f);
  u = (u + 0x7FFFu + ((u >> 16) & 1u)) >> 16;   // RNE
  return (u16)u;
}
__device__ __forceinline__ float b2f(u16 h){ return __uint_as_float(((u32)h) << 16); }

__device__ __forceinline__ void gload16(const void* g, void* l){
  __builtin_amdgcn_global_load_lds((__attribute__((address_space(1))) void*)(g),
                                   (__attribute__((address_space(3))) void*)(l), 16, 0, 0);
}

// ---------- both W transposes in one launch: z<8 -> W1, z>=8 -> W2 ----------
__global__ __launch_bounds__(256) void transpose_cvt2_kernel(const float* __restrict__ W1,
                                                             const float* __restrict__ W2,
                                                             u16* __restrict__ w1t,
                                                             u16* __restrict__ w2t){
  __shared__ float t[64][65];
  int z = blockIdx.z;
  const float* src; u16* dst; int R, C, c0, r0; size_t eo;
  if (z < 8){
    src = W1; dst = w1t; R = 1024; C = 4096;
    c0 = blockIdx.x * 64; r0 = blockIdx.y * 64;
    eo = (size_t)R * C * z;
  } else {
    src = W2; dst = w2t; R = 4096; C = 1024;
    c0 = blockIdx.y * 64; r0 = blockIdx.x * 64;
    eo = (size_t)R * C * (z - 8);
  }
  int tid = threadIdx.x;
  int lr = tid >> 4, lc4 = (tid & 15) * 4;
  #pragma unroll
  for (int i = 0; i < 4; i++){
    int r = lr + i * 16;
    float4 v = *(const float4*)&src[eo + (size_t)(r0 + r) * C + c0 + lc4];
    t[r][lc4] = v.x; t[r][lc4 + 1] = v.y; t[r][lc4 + 2] = v.z; t[r][lc4 + 3] = v.w;
  }
  __syncthreads();
  #pragma unroll
  for (int i = 0; i < 4; i++){
    int c = lr + i * 16;
    u16x4 o = { f2b(t[lc4][c]), f2b(t[lc4 + 1][c]), f2b(t[lc4 + 2][c]), f2b(t[lc4 + 3][c]) };
    *(u16x4*)&dst[eo + (size_t)(c0 + c) * R + r0 + lc4] = o;
  }
}

// ---------- gating v2 (R7, proven): register weights, batched epilogue ----------
__global__ __launch_bounds__(256) void gating_kernel(const float* __restrict__ x,
                                                     const float* __restrict__ nz,
                                                     const float* __restrict__ wg,
                                                     const float* __restrict__ wn,
                                                     int* __restrict__ counts,
                                                     int4* __restrict__ rowinfo,
                                                     float* __restrict__ loadrow,
                                                     u16* __restrict__ xb){
  __shared__ float wpart[16][4][17];
  int tid = threadIdx.x, w = tid >> 6, lane = tid & 63;
  int d0 = w * 256 + lane * 4;
  float4 wgA[4], wgB[4], wnA[4], wnB[4];
  #pragma unroll
  for (int k = 0; k < 4; k++){
    wgA[k] = *(const float4*)&wg[(d0 + k) * 8];
    wgB[k] = *(const float4*)&wg[(d0 + k) * 8 + 4];
    wnA[k] = *(const float4*)&wn[(d0 + k) * 8];
    wnB[k] = *(const float4*)&wn[(d0 + k) * 8 + 4];
  }
  int rbase = blockIdx.x * 16;
  for (int r = 0; r < 16; r++){
    int row = rbase + r;
    float4 xv = *(const float4*)&x[(size_t)row * 1024 + d0];
    u16x4 xo = { f2b(xv.x), f2b(xv.y), f2b(xv.z), f2b(xv.w) };
    *(u16x4*)&xb[(size_t)row * 1024 + d0] = xo;
    float ag[8], an[8];
    #pragma unroll
    for (int e = 0; e < 8; e++){ ag[e] = 0.f; an[e] = 0.f; }
    float xk[4] = { xv.x, xv.y, xv.z, xv.w };
    #pragma unroll
    for (int k = 0; k < 4; k++){
      ag[0] = fmaf(xk[k], wgA[k].x, ag[0]); ag[1] = fmaf(xk[k], wgA[k].y, ag[1]);
      ag[2] = fmaf(xk[k], wgA[k].z, ag[2]); ag[3] = fmaf(xk[k], wgA[k].w, ag[3]);
      ag[4] = fmaf(xk[k], wgB[k].x, ag[4]); ag[5] = fmaf(xk[k], wgB[k].y, ag[5]);
      ag[6] = fmaf(xk[k], wgB[k].z, ag[6]); ag[7] = fmaf(xk[k], wgB[k].w, ag[7]);
      an[0] = fmaf(xk[k], wnA[k].x, an[0]); an[1] = fmaf(xk[k], wnA[k].y, an[1]);
      an[2] = fmaf(xk[k], wnA[k].z, an[2]); an[3] = fmaf(xk[k], wnA[k].w, an[3]);
      an[4] = fmaf(xk[k], wnB[k].x, an[4]); an[5] = fmaf(xk[k], wnB[k].y, an[5]);
      an[6] = fmaf(xk[k], wnB[k].z, an[6]); an[7] = fmaf(xk[k], wnB[k].w, an[7]);
    }
    #pragma unroll
    for (int off = 32; off >= 1; off >>= 1){
      #pragma unroll
      for (int e = 0; e < 8; e++){
        ag[e] += __shfl_xor(ag[e], off, 64);
        an[e] += __shfl_xor(an[e], off, 64);
      }
    }
    if (lane == 0){
      #pragma unroll
      for (int e = 0; e < 8; e++){
        wpart[r][w][e] = ag[e];
        wpart[r][w][8 + e] = an[e];
      }
    }
  }
  __syncthreads();
  if (tid < 16){
    int r = tid, row = rbase + r;
    float cg[16];
    #pragma unroll
    for (int v = 0; v < 16; v++)
      cg[v] = wpart[r][0][v] + wpart[r][1][v] + wpart[r][2][v] + wpart[r][3][v];
    float clean[8], sd[8], noisy[8];
    #pragma unroll
    for (int e = 0; e < 8; e++){
      clean[e] = cg[e];
      float v = cg[8 + e];
      float sp = fmaxf(v, 0.f) + log1pf(expf(-fabsf(v)));
      sd[e] = sp + 0.01f;
      noisy[e] = clean[e] + nz[row * 8 + e] * sd[e];
    }
    int i0 = 0, i1 = -1;
    float b0 = -3.4e38f, b1v = -3.4e38f, b2v = -3.4e38f;
    #pragma unroll
    for (int j = 0; j < 8; j++){
      float t = noisy[j];
      if (t > b0){ b2v = b1v; b1v = b0; i1 = i0; b0 = t; i0 = j; }
      else if (t > b1v){ b2v = b1v; b1v = t; i1 = j; }
      else if (t > b2v){ b2v = t; }
    }
    float eg = expf(b1v - b0);
    float g0 = 1.f / (1.f + eg), g1 = eg / (1.f + eg);
    rowinfo[row] = make_int4(i0, i1, __float_as_int(g0), __float_as_int(g1));
    atomicAdd(&counts[i0], 1);
    atomicAdd(&counts[i1], 1);
    float thr_in = b2v, thr_out = b1v;
    #pragma unroll
    for (int e = 0; e < 8; e++){
      bool isin = noisy[e] > thr_in;
      float thr = isin ? thr_in : thr_out;
      float z = (clean[e] - thr) / sd[e];
      loadrow[row * 8 + e] = 0.5f * (1.f + erff(z * 0.70710678118654752f));
    }
  }
}

// ---------- fill dispatch lists (scan fused: block-local prefix, block 0 publishes) ----------
__global__ __launch_bounds__(256) void fill_kernel(const int* __restrict__ counts,
                                                   const int4* __restrict__ rowinfo,
                                                   int* __restrict__ offs,
                                                   int* __restrict__ cnt2,
                                                   int* __restrict__ tok,
                                                   int* __restrict__ slot_of,
                                                   int* __restrict__ btab){
  __shared__ int loff[8];
  if (threadIdx.x == 0){
    int s = 0;
    for (int e = 0; e < 8; e++){ loff[e] = s; s += counts[e]; }
    if (blockIdx.x == 0){
      int nb = 0;
      for (int e = 0; e < 8; e++){
        offs[e] = loff[e];
        int nbe = (counts[e] + 255) >> 8;
        for (int t = 0; t < nbe; t++) btab[nb++] = (e << 16) | t;
      }
      offs[15] = nb;
    }
  }
  __syncthreads();
  int r = blockIdx.x * 256 + threadIdx.x;
  int4 ri = rowinfo[r];
  int p0 = atomicAdd(&cnt2[ri.x], 1);
  int s0 = loff[ri.x] + p0;
  tok[s0] = r; slot_of[2 * r] = s0;
  int p1 = atomicAdd(&cnt2[ri.y], 1);
  int s1 = loff[ri.y] + p1;
  tok[s1] = r; slot_of[2 * r + 1] = s1;
}

// ---------- grouped GEMM, 256x256, 8-phase counted-vmcnt + early-read overlap ----------
// Schedule and epilogue identical to R8 (the best-measured variant: 228us/dispatch,
// MfmaUtil 26.5%, conflicts 0). R9's LDS-staged epilogue REGRESSED (233us, +68MB
// FETCH) and is reverted.
template<int KDIM, bool GATHER, bool RELU, bool PSPLIT>
__global__ __launch_bounds__(512, 1) void ffn8_kernel(
    const u16* __restrict__ Ag, const u16* __restrict__ Bt,
    const float* __restrict__ bias, u16* __restrict__ outp,
    const int* __restrict__ counts, const int* __restrict__ offs,
    const int* __restrict__ btab, const int* __restrict__ tok,
    int nc, int klen, int ostr, size_t pstride)
{
  __shared__ u16 As[2][2][128 * 64];
  __shared__ u16 Bs[2][2][128 * 64];

  int gx = gridDim.x;
  int lin = blockIdx.y * gx + blockIdx.x;
  int total = gx * gridDim.y, chunk = total >> 3;
  int swz = (lin & 7) * chunk + (lin >> 3);       // bijective: total % 8 == 0
  int bx = swz % gx, tq = swz / gx;
  int nblk = offs[15];
  if (bx >= nblk) return;
  int kh = tq / nc;
  int tn = tq - kh * nc;
  int kbase = kh * klen;
  int niter = klen >> 7;                          // klen/128 (2 tiles/iter)
  int et = btab[bx]; int e = et >> 16, tm = et & 0xffff;
  int cnt = counts[e], off_e = offs[e];

  int tid = threadIdx.x, lane = tid & 63;
  int wid = tid >> 6, wm = wid >> 2, wn = wid & 3;

  // staging source byte offsets (source pre-swizzled; LDS dest linear — rule #21)
  int rl0 = tid >> 3, c8 = tid & 7;
  const char* Abase = (const char*)Ag + (size_t)kbase * 2;
  const char* Bbase = (const char*)(Bt + (size_t)e * 4194304) + (size_t)kbase * 2;
  u32 aoff[4], boff[4];
  #pragma unroll
  for (int h = 0; h < 2; h++)
    #pragma unroll
    for (int r = 0; r < 2; r++){
      int rl = h * 128 + r * 64 + rl0;
      int c8s = c8 ^ (rl & 7);
      int rr = tm * 256 + rl;
      int rc = (rr < cnt) ? rr : (cnt - 1);
      size_t arow = GATHER ? (size_t)tok[off_e + rc] : (size_t)(off_e + rc);
      aoff[h * 2 + r] = (u32)(arow * (KDIM * 2) + c8s * 16);
      boff[h * 2 + r] = (u32)((size_t)(tn * 256 + rl) * (KDIM * 2) + c8s * 16);
    }
  int ldst = (tid & ~63) * 8;   // wave-uniform linear LDS dest (elements)

  auto stA = [&](int b, int h, int t){
    const char* s = Abase + (size_t)t * 128;
    gload16(s + aoff[h * 2 + 0], &As[b][h][ldst]);
    gload16(s + aoff[h * 2 + 1], &As[b][h][4096 + ldst]);
  };
  auto stB = [&](int b, int h, int t){
    const char* s = Bbase + (size_t)t * 128;
    gload16(s + boff[h * 2 + 0], &Bs[b][h][ldst]);
    gload16(s + boff[h * 2 + 1], &Bs[b][h][4096 + ldst]);
  };

  int lm = lane & 15, lkb = (lane >> 4) * 8;
  short8 Ar[4][2], Br[2][2][2];
  auto ldA = [&](int b, int rh){
    #pragma unroll
    for (int ii = 0; ii < 4; ii++){
      int rl = rh * 64 + ii * 16 + lm;
      #pragma unroll
      for (int ks = 0; ks < 2; ks++){
        int idx = (rl * 64 + ks * 32 + lkb) ^ ((rl & 7) << 3);
        Ar[ii][ks] = *(const short8*)&As[b][wm][idx];
      }
    }
  };
  auto ldB = [&](int b, int ch){
    #pragma unroll
    for (int jj = 0; jj < 2; jj++){
      int rb = wn * 64 + ch * 32 + jj * 16 + lm;
      int hB = rb >> 7, rl = rb & 127;
      #pragma unroll
      for (int ks = 0; ks < 2; ks++){
        int idx = (rl * 64 + ks * 32 + lkb) ^ ((rl & 7) << 3);
        Br[ch][jj][ks] = *(const short8*)&Bs[b][hB][idx];
      }
    }
  };

  f32x4 acc[8][4];
  #pragma unroll
  for (int i = 0; i < 8; i++)
    #pragma unroll
    for (int j = 0; j < 4; j++) acc[i][j] = (f32x4){0.f, 0.f, 0.f, 0.f};

  auto mfmaQ = [&](int rh, int ch){
    __builtin_amdgcn_s_setprio(1);
    #pragma unroll
    for (int ks = 0; ks < 2; ks++)
      #pragma unroll
      for (int ii = 0; ii < 4; ii++)
        #pragma unroll
        for (int jj = 0; jj < 2; jj++)
          acc[rh * 4 + ii][ch * 2 + jj] = __builtin_amdgcn_mfma_f32_16x16x32_bf16(
              Ar[ii][ks], Br[ch][jj][ks], acc[rh * 4 + ii][ch * 2 + jj], 0, 0, 0);
    __builtin_amdgcn_s_setprio(0);
  };

  // prologue: t0 all 4 halves -> buf0; t1's B-h0, A-h0 -> buf1
  stA(0, 0, 0); stA(0, 1, 0); stB(0, 0, 0); stB(0, 1, 0);
  stB(1, 0, 1); stA(1, 0, 1);
  VM4; BARR;

  for (int j = 0; j < niter - 1; ++j){
    int t1 = 2 * j + 1, t2 = 2 * j + 2, t3 = 2 * j + 3;
    // P1
    ldA(0, 0); ldB(0, 0);
    stA(1, 1, t1);
    BARR; mfmaQ(0, 0); ldB(0, 1); BARR;
    // P2
    stB(1, 1, t1);
    BARR; mfmaQ(0, 1); ldA(0, 1); BARR;
    // P3
    stB(0, 0, t2);
    BARR; mfmaQ(1, 1); BARR;
    // P4 (Br[0] regs still hold buf0 ch0)
    stA(0, 0, t2);
    BARR; mfmaQ(1, 0); VM4; BARR;
    // P5
    ldA(1, 0); ldB(1, 0);
    stA(0, 1, t2);
    BARR; mfmaQ(0, 0); ldB(1, 1); BARR;
    // P6
    stB(0, 1, t2);
    BARR; mfmaQ(0, 1); ldA(1, 1); BARR;
    // P7
    stB(1, 0, t3);
    BARR; mfmaQ(1, 1); BARR;
    // P8
    stA(1, 0, t3);
    BARR; mfmaQ(1, 0); VM4; BARR;
  }

  { // peeled last iteration: only P1/P2 stage (complete tile NT-1), full drain at P4
    int t1 = (klen >> 6) - 1;
    ldA(0, 0); ldB(0, 0);
    stA(1, 1, t1);
    BARR; mfmaQ(0, 0); ldB(0, 1); BARR;
    stB(1, 1, t1);
    BARR; mfmaQ(0, 1); ldA(0, 1); BARR;
    BARR; mfmaQ(1, 1); BARR;
    mfmaQ(1, 0); VM0; BARR;
    ldA(1, 0); ldB(1, 0);
    BARR; mfmaQ(0, 0); ldB(1, 1); BARR;
    BARR; mfmaQ(0, 1); ldA(1, 1); BARR;
    BARR; mfmaQ(1, 1); BARR;
    mfmaQ(1, 0);
  }

  // epilogue: direct C write (R8-proven)
  int lr = (lane >> 4) * 4;
  u16* po = outp + (PSPLIT ? (size_t)kh * pstride : 0);
  #pragma unroll
  for (int i = 0; i < 8; i++){
    int row_l = wm * 128 + i * 16 + lr;
    #pragma unroll
    for (int jj = 0; jj < 4; jj++){
      int col = tn * 256 + wn * 64 + jj * 16 + lm;
      float bv = PSPLIT ? 0.f : bias[e * ostr + col];
      #pragma unroll
      for (int q = 0; q < 4; q++){
        int r = tm * 256 + row_l + q;
        if (r < cnt){
          float v = acc[i][jj][q] + bv;
          if (RELU) v = fmaxf(v, 0.f);
          po[(size_t)(off_e + r) * ostr + col] = f2b(v);
        }
      }
    }
  }
}

// ---------- combine: 4 rows/block, wave-per-row, 512B read segments ----------
__global__ __launch_bounds__(256) void combine_kernel(const u16* __restrict__ pb,
                                                      const float* __restrict__ b2,
                                                      const int4* __restrict__ rowinfo,
                                                      const int* __restrict__ slot_of,
                                                      float* __restrict__ y){
  const size_t PS = (size_t)16384 * 1024;
  int w = threadIdx.x >> 6, lane = threadIdx.x & 63;
  int row = blockIdx.x * 4 + w;
  int4 ri = rowinfo[row];
  float g0 = __int_as_float(ri.z), g1 = __int_as_float(ri.w);
  int s0 = slot_of[2 * row], s1 = slot_of[2 * row + 1];
  const u16* pa = pb + ((size_t)s0 << 10);
  const u16* pbb = pb + ((size_t)s1 << 10);
  #pragma unroll
  for (int k = 0; k < 4; k++){
    int c4 = k * 256 + lane * 4;
    float4 sum0 = *(const float4*)&b2[(ri.x << 10) + c4];
    float4 sum1 = *(const float4*)&b2[(ri.y << 10) + c4];
    #pragma unroll
    for (int kh = 0; kh < 4; kh++){
      u16x4 a = *(const u16x4*)&pa[kh * PS + c4];
      u16x4 b = *(const u16x4*)&pbb[kh * PS + c4];
      sum0.x += b2f(a.x); sum0.y += b2f(a.y); sum0.z += b2f(a.z); sum0.w += b2f(a.w);
      sum1.x += b2f(b.x); sum1.y += b2f(b.y); sum1.z += b2f(b.z); sum1.w += b2f(b.w);
    }
    float4 o;
    o.x = g0 * sum0.x + g1 * sum1.x;
    o.y = g0 * sum0.y + g1 * sum1.y;
    o.z = g0 * sum0.z + g1 * sum1.z;
    o.w = g0 * sum0.w + g1 * sum1.w;
    *(float4*)&y[(size_t)row * 1024 + c4] = o;
  }
}

// ---------- loss stage 1: 32 blocks x 256 rows -> partials[32][16] ----------
__global__ __launch_bounds__(256) void loss1_kernel(const int4* __restrict__ rowinfo,
                                                    const float* __restrict__ loadrow,
                                                    float* __restrict__ partials){
  __shared__ float part[16][256];
  int tid = threadIdx.x;
  int r = blockIdx.x * 256 + tid;
  int4 ri = rowinfo[r];
  float g0 = __int_as_float(ri.z), g1 = __int_as_float(ri.w);
  f32x4 l0 = *(const f32x4*)&loadrow[r * 8];
  f32x4 l1 = *(const f32x4*)&loadrow[r * 8 + 4];
  #pragma unroll
  for (int e = 0; e < 8; e++){
    part[e][tid] = ((ri.x == e) ? g0 : 0.f) + ((ri.y == e) ? g1 : 0.f);
    part[8 + e][tid] = (e < 4) ? l0[e & 3] : l1[e & 3];
  }
  __syncthreads();
  #pragma unroll
  for (int s = 128; s >= 1; s >>= 1){
    if (tid < s){
      #pragma unroll
      for (int e = 0; e < 16; e++) part[e][tid] += part[e][tid + s];
    }
    __syncthreads();
  }
  if (tid < 16) partials[blockIdx.x * 16 + tid] = part[tid][0];
}

// ---------- loss stage 2 ----------
__global__ __launch_bounds__(64) void loss2_kernel(const float* __restrict__ partials,
                                                   float* __restrict__ out_loss){
  __shared__ float tot[16];
  int tid = threadIdx.x;
  if (tid < 16){
    float s = 0.f;
    for (int b = 0; b < 32; b++) s += partials[b * 16 + tid];
    tot[tid] = s;
  }
  __syncthreads();
  if (tid == 0){
    float mi = 0.f, ml = 0.f;
    for (int e = 0; e < 8; e++){ mi += tot[e]; ml += tot[8 + e]; }
    mi *= 0.125f; ml *= 0.125f;
    float vi = 0.f, vl = 0.f;
    for (int e = 0; e < 8; e++){
      float di = tot[e] - mi; vi += di * di;
      float dl = tot[8 + e] - ml; vl += dl * dl;
    }
    vi /= 7.f; vl /= 7.f;
    float cvi = vi / (mi * mi + 1e-10f);
    float cvl = vl / (ml * ml + 1e-10f);
    out_loss[0] = 0.01f * (cvi + cvl);
  }
}

// ---------- launch ----------
extern "C" void kernel_launch(void* const* d_in, const int* in_sizes, int n_in,
                              void* d_out, int out_size, void* d_ws, size_t ws_size,
                              hipStream_t stream){
  const float* x  = (const float*)d_in[0];
  const float* nz = (const float*)d_in[1];
  const float* wg = (const float*)d_in[2];
  const float* wn = (const float*)d_in[3];
  const float* W1 = (const float*)d_in[4];
  const float* b1 = (const float*)d_in[5];
  const float* W2 = (const float*)d_in[6];
  const float* b2 = (const float*)d_in[7];
  float* y = (float*)d_out;
  float* loss = y + (size_t)8192 * 1024;

  char* ws = (char*)d_ws;
  size_t o = 0;
  auto alloc = [&](size_t bytes){ size_t r = o; o += (bytes + 255) & ~(size_t)255; return r; };
  int*  counts  = (int*)(ws + alloc(64));
  int*  cnt2    = (int*)(ws + alloc(64));
  int*  offs    = (int*)(ws + alloc(64));
  int*  btab    = (int*)(ws + alloc(1024));
  int4* rowinfo = (int4*)(ws + alloc((size_t)8192 * 16));
  int*  slot_of = (int*)(ws + alloc((size_t)16384 * 4));
  int*  tok     = (int*)(ws + alloc((size_t)16384 * 4));
  float* loadrow = (float*)(ws + alloc((size_t)8192 * 8 * 4));
  float* partials = (float*)(ws + alloc(32 * 16 * 4));
  u16*  xb      = (u16*)(ws + alloc((size_t)8192 * 1024 * 2));
  u16*  w1t     = (u16*)(ws + alloc((size_t)8 * 1024 * 4096 * 2));
  u16*  w2t     = (u16*)(ws + alloc((size_t)8 * 1024 * 4096 * 2));
  u16*  h_buf   = (u16*)(ws + alloc((size_t)16384 * 4096 * 2));
  u16*  pbuf    = (u16*)(ws + alloc((size_t)4 * 16384 * 1024 * 2));
  if (o > ws_size) return;

  hipMemsetAsync(ws, 0, 768, stream);  // counts, cnt2, offs

  gating_kernel<<<512, 256, 0, stream>>>(x, nz, wg, wn, counts, rowinfo, loadrow, xb);
  transpose_cvt2_kernel<<<dim3(64, 16, 16), 256, 0, stream>>>(W1, W2, w1t, w2t);
  fill_kernel<<<32, 256, 0, stream>>>(counts, rowinfo, offs, cnt2, tok, slot_of, btab);
  // ffn1: K=1024, bf16 out with bias+relu (nc=16 col tiles, kh always 0)
  ffn8_kernel<1024, true, true, false><<<dim3(72, 16), 512, 0, stream>>>(
      xb, w1t, b1, h_buf, counts, offs, btab, tok, 16, 1024, 4096, 0);
  // ffn2: K split 4x1024 in ONE dispatch (nc=4 col tiles x 4 kh), bf16 partials
  ffn8_kernel<4096, false, false, true><<<dim3(72, 16), 512, 0, stream>>>(
      h_buf, w2t, nullptr, pbuf, counts, offs, btab, tok, 4, 1024, 1024,
      (size_t)16384 * 1024);
  combine_kernel<<<2048, 256, 0, stream>>>(pbuf, b2, rowinfo, slot_of, y);
  loss1_kernel<<<32, 256, 0, stream>>>(rowinfo, loadrow, partials);
  loss2_kernel<<<1, 64, 0, stream>>>(partials, loss);
}

// Round 11
// 632.178 us; speedup vs baseline: 1.1232x; 1.0814x over previous
//
#include <hip/hip_runtime.h>

typedef unsigned short u16;
typedef unsigned int u32;
typedef __attribute__((ext_vector_type(4))) float f32x4;
typedef __attribute__((ext_vector_type(8))) short short8;
typedef __attribute__((ext_vector_type(4))) unsigned short u16x4;

#define BARR __builtin_amdgcn_s_barrier()
#define VM4  asm volatile("s_waitcnt vmcnt(4)" ::: "memory")
#define VM0  asm volatile("s_waitcnt vmcnt(0)" ::: "memory")

// ---------- helpers ----------
__device__ __forceinline__ u16 f2b(float f){
  u32 u = __float_as_uint(f);
  u = (u + 0x7FFFu + ((u >> 16) & 1u)) >> 16;   // RNE
  return (u16)u;
}
__device__ __forceinline__ float b2f(u16 h){ return __uint_as_float(((u32)h) << 16); }

__device__ __forceinline__ void gload16(const void* g, void* l){
  __builtin_amdgcn_global_load_lds((__attribute__((address_space(1))) void*)(g),
                                   (__attribute__((address_space(3))) void*)(l), 16, 0, 0);
}

// ---------- prep: gating (blocks 0..511) + W1/W2 transpose (blocks 512..16895) ----------
// Independent work co-scheduled in one dispatch: gating is VALU/latency-bound,
// transpose is BW-bound; small LDS (17.4KB union) gives ~9 blocks/CU co-residency.
__global__ __launch_bounds__(256) void prep_kernel(const float* __restrict__ x,
                                                   const float* __restrict__ nz,
                                                   const float* __restrict__ wg,
                                                   const float* __restrict__ wn,
                                                   const float* __restrict__ W1,
                                                   const float* __restrict__ W2,
                                                   int* __restrict__ counts,
                                                   int4* __restrict__ rowinfo,
                                                   float* __restrict__ loadrow,
                                                   u16* __restrict__ xb,
                                                   u16* __restrict__ w1t,
                                                   u16* __restrict__ w2t){
  __shared__ __align__(16) char SM[17408];
  int b = blockIdx.x;
  int tid = threadIdx.x;
  if (b >= 512){
    // ---- transpose tile path ----
    int t = b - 512;
    const float* src; u16* dst; int R, C, r0, c0; size_t eo;
    if (t < 8192){                       // W1: [1024][4096] -> w1t [4096][1024]
      src = W1; dst = w1t; R = 1024; C = 4096;
      int e = t >> 10, rem = t & 1023;
      c0 = (rem & 63) * 64; r0 = (rem >> 6) * 64;
      eo = (size_t)R * C * e;
    } else {                             // W2: [4096][1024] -> w2t [1024][4096]
      t -= 8192;
      src = W2; dst = w2t; R = 4096; C = 1024;
      int e = t >> 10, rem = t & 1023;
      r0 = (rem & 63) * 64; c0 = (rem >> 6) * 64;
      eo = (size_t)R * C * e;
    }
    float (*tt)[65] = (float(*)[65])SM;
    int lr = tid >> 4, lc4 = (tid & 15) * 4;
    #pragma unroll
    for (int i = 0; i < 4; i++){
      int r = lr + i * 16;
      float4 v = *(const float4*)&src[eo + (size_t)(r0 + r) * C + c0 + lc4];
      tt[r][lc4] = v.x; tt[r][lc4 + 1] = v.y; tt[r][lc4 + 2] = v.z; tt[r][lc4 + 3] = v.w;
    }
    __syncthreads();
    #pragma unroll
    for (int i = 0; i < 4; i++){
      int c = lr + i * 16;
      u16x4 o = { f2b(tt[lc4][c]), f2b(tt[lc4 + 1][c]), f2b(tt[lc4 + 2][c]), f2b(tt[lc4 + 3][c]) };
      *(u16x4*)&dst[eo + (size_t)(c0 + c) * R + r0 + lc4] = o;
    }
    return;
  }
  // ---- gating path (R7-proven body) ----
  float (*wpart)[4][17] = (float(*)[4][17])SM;
  int w = tid >> 6, lane = tid & 63;
  int d0 = w * 256 + lane * 4;
  float4 wgA[4], wgB[4], wnA[4], wnB[4];
  #pragma unroll
  for (int k = 0; k < 4; k++){
    wgA[k] = *(const float4*)&wg[(d0 + k) * 8];
    wgB[k] = *(const float4*)&wg[(d0 + k) * 8 + 4];
    wnA[k] = *(const float4*)&wn[(d0 + k) * 8];
    wnB[k] = *(const float4*)&wn[(d0 + k) * 8 + 4];
  }
  int rbase = b * 16;
  for (int r = 0; r < 16; r++){
    int row = rbase + r;
    float4 xv = *(const float4*)&x[(size_t)row * 1024 + d0];
    u16x4 xo = { f2b(xv.x), f2b(xv.y), f2b(xv.z), f2b(xv.w) };
    *(u16x4*)&xb[(size_t)row * 1024 + d0] = xo;
    float ag[8], an[8];
    #pragma unroll
    for (int e = 0; e < 8; e++){ ag[e] = 0.f; an[e] = 0.f; }
    float xk[4] = { xv.x, xv.y, xv.z, xv.w };
    #pragma unroll
    for (int k = 0; k < 4; k++){
      ag[0] = fmaf(xk[k], wgA[k].x, ag[0]); ag[1] = fmaf(xk[k], wgA[k].y, ag[1]);
      ag[2] = fmaf(xk[k], wgA[k].z, ag[2]); ag[3] = fmaf(xk[k], wgA[k].w, ag[3]);
      ag[4] = fmaf(xk[k], wgB[k].x, ag[4]); ag[5] = fmaf(xk[k], wgB[k].y, ag[5]);
      ag[6] = fmaf(xk[k], wgB[k].z, ag[6]); ag[7] = fmaf(xk[k], wgB[k].w, ag[7]);
      an[0] = fmaf(xk[k], wnA[k].x, an[0]); an[1] = fmaf(xk[k], wnA[k].y, an[1]);
      an[2] = fmaf(xk[k], wnA[k].z, an[2]); an[3] = fmaf(xk[k], wnA[k].w, an[3]);
      an[4] = fmaf(xk[k], wnB[k].x, an[4]); an[5] = fmaf(xk[k], wnB[k].y, an[5]);
      an[6] = fmaf(xk[k], wnB[k].z, an[6]); an[7] = fmaf(xk[k], wnB[k].w, an[7]);
    }
    #pragma unroll
    for (int off = 32; off >= 1; off >>= 1){
      #pragma unroll
      for (int e = 0; e < 8; e++){
        ag[e] += __shfl_xor(ag[e], off, 64);
        an[e] += __shfl_xor(an[e], off, 64);
      }
    }
    if (lane == 0){
      #pragma unroll
      for (int e = 0; e < 8; e++){
        wpart[r][w][e] = ag[e];
        wpart[r][w][8 + e] = an[e];
      }
    }
  }
  __syncthreads();
  if (tid < 16){
    int r = tid, row = rbase + r;
    float cg[16];
    #pragma unroll
    for (int v = 0; v < 16; v++)
      cg[v] = wpart[r][0][v] + wpart[r][1][v] + wpart[r][2][v] + wpart[r][3][v];
    float clean[8], sd[8], noisy[8];
    #pragma unroll
    for (int e = 0; e < 8; e++){
      clean[e] = cg[e];
      float v = cg[8 + e];
      float sp = fmaxf(v, 0.f) + log1pf(expf(-fabsf(v)));
      sd[e] = sp + 0.01f;
      noisy[e] = clean[e] + nz[row * 8 + e] * sd[e];
    }
    int i0 = 0, i1 = -1;
    float b0 = -3.4e38f, b1v = -3.4e38f, b2v = -3.4e38f;
    #pragma unroll
    for (int j = 0; j < 8; j++){
      float t = noisy[j];
      if (t > b0){ b2v = b1v; b1v = b0; i1 = i0; b0 = t; i0 = j; }
      else if (t > b1v){ b2v = b1v; b1v = t; i1 = j; }
      else if (t > b2v){ b2v = t; }
    }
    float eg = expf(b1v - b0);
    float g0 = 1.f / (1.f + eg), g1 = eg / (1.f + eg);
    rowinfo[row] = make_int4(i0, i1, __float_as_int(g0), __float_as_int(g1));
    atomicAdd(&counts[i0], 1);
    atomicAdd(&counts[i1], 1);
    float thr_in = b2v, thr_out = b1v;
    #pragma unroll
    for (int e = 0; e < 8; e++){
      bool isin = noisy[e] > thr_in;
      float thr = isin ? thr_in : thr_out;
      float z = (clean[e] - thr) / sd[e];
      loadrow[row * 8 + e] = 0.5f * (1.f + erff(z * 0.70710678118654752f));
    }
  }
}

// ---------- fill dispatch lists (scan fused: block-local prefix, block 0 publishes) ----------
__global__ __launch_bounds__(256) void fill_kernel(const int* __restrict__ counts,
                                                   const int4* __restrict__ rowinfo,
                                                   int* __restrict__ offs,
                                                   int* __restrict__ cnt2,
                                                   int* __restrict__ tok,
                                                   int* __restrict__ slot_of,
                                                   int* __restrict__ btab){
  __shared__ int loff[8];
  if (threadIdx.x == 0){
    int s = 0;
    for (int e = 0; e < 8; e++){ loff[e] = s; s += counts[e]; }
    if (blockIdx.x == 0){
      int nb = 0;
      for (int e = 0; e < 8; e++){
        offs[e] = loff[e];
        int nbe = (counts[e] + 255) >> 8;
        for (int t = 0; t < nbe; t++) btab[nb++] = (e << 16) | t;
      }
      offs[15] = nb;
    }
  }
  __syncthreads();
  int r = blockIdx.x * 256 + threadIdx.x;
  int4 ri = rowinfo[r];
  int p0 = atomicAdd(&cnt2[ri.x], 1);
  int s0 = loff[ri.x] + p0;
  tok[s0] = r; slot_of[2 * r] = s0;
  int p1 = atomicAdd(&cnt2[ri.y], 1);
  int s1 = loff[ri.y] + p1;
  tok[s1] = r; slot_of[2 * r + 1] = s1;
}

// ---------- grouped GEMM, 256x256, 8-phase counted-vmcnt + early-read overlap ----------
// Byte-identical to R10 (proven 228us/dispatch, MfmaUtil 26.5%, conflicts 0).
template<int KDIM, bool GATHER, bool RELU, bool PSPLIT>
__global__ __launch_bounds__(512, 1) void ffn8_kernel(
    const u16* __restrict__ Ag, const u16* __restrict__ Bt,
    const float* __restrict__ bias, u16* __restrict__ outp,
    const int* __restrict__ counts, const int* __restrict__ offs,
    const int* __restrict__ btab, const int* __restrict__ tok,
    int nc, int klen, int ostr, size_t pstride)
{
  __shared__ u16 As[2][2][128 * 64];
  __shared__ u16 Bs[2][2][128 * 64];

  int gx = gridDim.x;
  int lin = blockIdx.y * gx + blockIdx.x;
  int total = gx * gridDim.y, chunk = total >> 3;
  int swz = (lin & 7) * chunk + (lin >> 3);       // bijective: total % 8 == 0
  int bx = swz % gx, tq = swz / gx;
  int nblk = offs[15];
  if (bx >= nblk) return;
  int kh = tq / nc;
  int tn = tq - kh * nc;
  int kbase = kh * klen;
  int niter = klen >> 7;                          // klen/128 (2 tiles/iter)
  int et = btab[bx]; int e = et >> 16, tm = et & 0xffff;
  int cnt = counts[e], off_e = offs[e];

  int tid = threadIdx.x, lane = tid & 63;
  int wid = tid >> 6, wm = wid >> 2, wn = wid & 3;

  // staging source byte offsets (source pre-swizzled; LDS dest linear — rule #21)
  int rl0 = tid >> 3, c8 = tid & 7;
  const char* Abase = (const char*)Ag + (size_t)kbase * 2;
  const char* Bbase = (const char*)(Bt + (size_t)e * 4194304) + (size_t)kbase * 2;
  u32 aoff[4], boff[4];
  #pragma unroll
  for (int h = 0; h < 2; h++)
    #pragma unroll
    for (int r = 0; r < 2; r++){
      int rl = h * 128 + r * 64 + rl0;
      int c8s = c8 ^ (rl & 7);
      int rr = tm * 256 + rl;
      int rc = (rr < cnt) ? rr : (cnt - 1);
      size_t arow = GATHER ? (size_t)tok[off_e + rc] : (size_t)(off_e + rc);
      aoff[h * 2 + r] = (u32)(arow * (KDIM * 2) + c8s * 16);
      boff[h * 2 + r] = (u32)((size_t)(tn * 256 + rl) * (KDIM * 2) + c8s * 16);
    }
  int ldst = (tid & ~63) * 8;   // wave-uniform linear LDS dest (elements)

  auto stA = [&](int b, int h, int t){
    const char* s = Abase + (size_t)t * 128;
    gload16(s + aoff[h * 2 + 0], &As[b][h][ldst]);
    gload16(s + aoff[h * 2 + 1], &As[b][h][4096 + ldst]);
  };
  auto stB = [&](int b, int h, int t){
    const char* s = Bbase + (size_t)t * 128;
    gload16(s + boff[h * 2 + 0], &Bs[b][h][ldst]);
    gload16(s + boff[h * 2 + 1], &Bs[b][h][4096 + ldst]);
  };

  int lm = lane & 15, lkb = (lane >> 4) * 8;
  short8 Ar[4][2], Br[2][2][2];
  auto ldA = [&](int b, int rh){
    #pragma unroll
    for (int ii = 0; ii < 4; ii++){
      int rl = rh * 64 + ii * 16 + lm;
      #pragma unroll
      for (int ks = 0; ks < 2; ks++){
        int idx = (rl * 64 + ks * 32 + lkb) ^ ((rl & 7) << 3);
        Ar[ii][ks] = *(const short8*)&As[b][wm][idx];
      }
    }
  };
  auto ldB = [&](int b, int ch){
    #pragma unroll
    for (int jj = 0; jj < 2; jj++){
      int rb = wn * 64 + ch * 32 + jj * 16 + lm;
      int hB = rb >> 7, rl = rb & 127;
      #pragma unroll
      for (int ks = 0; ks < 2; ks++){
        int idx = (rl * 64 + ks * 32 + lkb) ^ ((rl & 7) << 3);
        Br[ch][jj][ks] = *(const short8*)&Bs[b][hB][idx];
      }
    }
  };

  f32x4 acc[8][4];
  #pragma unroll
  for (int i = 0; i < 8; i++)
    #pragma unroll
    for (int j = 0; j < 4; j++) acc[i][j] = (f32x4){0.f, 0.f, 0.f, 0.f};

  auto mfmaQ = [&](int rh, int ch){
    __builtin_amdgcn_s_setprio(1);
    #pragma unroll
    for (int ks = 0; ks < 2; ks++)
      #pragma unroll
      for (int ii = 0; ii < 4; ii++)
        #pragma unroll
        for (int jj = 0; jj < 2; jj++)
          acc[rh * 4 + ii][ch * 2 + jj] = __builtin_amdgcn_mfma_f32_16x16x32_bf16(
              Ar[ii][ks], Br[ch][jj][ks], acc[rh * 4 + ii][ch * 2 + jj], 0, 0, 0);
    __builtin_amdgcn_s_setprio(0);
  };

  // prologue: t0 all 4 halves -> buf0; t1's B-h0, A-h0 -> buf1
  stA(0, 0, 0); stA(0, 1, 0); stB(0, 0, 0); stB(0, 1, 0);
  stB(1, 0, 1); stA(1, 0, 1);
  VM4; BARR;

  for (int j = 0; j < niter - 1; ++j){
    int t1 = 2 * j + 1, t2 = 2 * j + 2, t3 = 2 * j + 3;
    // P1
    ldA(0, 0); ldB(0, 0);
    stA(1, 1, t1);
    BARR; mfmaQ(0, 0); ldB(0, 1); BARR;
    // P2
    stB(1, 1, t1);
    BARR; mfmaQ(0, 1); ldA(0, 1); BARR;
    // P3
    stB(0, 0, t2);
    BARR; mfmaQ(1, 1); BARR;
    // P4 (Br[0] regs still hold buf0 ch0)
    stA(0, 0, t2);
    BARR; mfmaQ(1, 0); VM4; BARR;
    // P5
    ldA(1, 0); ldB(1, 0);
    stA(0, 1, t2);
    BARR; mfmaQ(0, 0); ldB(1, 1); BARR;
    // P6
    stB(0, 1, t2);
    BARR; mfmaQ(0, 1); ldA(1, 1); BARR;
    // P7
    stB(1, 0, t3);
    BARR; mfmaQ(1, 1); BARR;
    // P8
    stA(1, 0, t3);
    BARR; mfmaQ(1, 0); VM4; BARR;
  }

  { // peeled last iteration: only P1/P2 stage (complete tile NT-1), full drain at P4
    int t1 = (klen >> 6) - 1;
    ldA(0, 0); ldB(0, 0);
    stA(1, 1, t1);
    BARR; mfmaQ(0, 0); ldB(0, 1); BARR;
    stB(1, 1, t1);
    BARR; mfmaQ(0, 1); ldA(0, 1); BARR;
    BARR; mfmaQ(1, 1); BARR;
    mfmaQ(1, 0); VM0; BARR;
    ldA(1, 0); ldB(1, 0);
    BARR; mfmaQ(0, 0); ldB(1, 1); BARR;
    BARR; mfmaQ(0, 1); ldA(1, 1); BARR;
    BARR; mfmaQ(1, 1); BARR;
    mfmaQ(1, 0);
  }

  // epilogue: direct C write (R8-proven)
  int lr = (lane >> 4) * 4;
  u16* po = outp + (PSPLIT ? (size_t)kh * pstride : 0);
  #pragma unroll
  for (int i = 0; i < 8; i++){
    int row_l = wm * 128 + i * 16 + lr;
    #pragma unroll
    for (int jj = 0; jj < 4; jj++){
      int col = tn * 256 + wn * 64 + jj * 16 + lm;
      float bv = PSPLIT ? 0.f : bias[e * ostr + col];
      #pragma unroll
      for (int q = 0; q < 4; q++){
        int r = tm * 256 + row_l + q;
        if (r < cnt){
          float v = acc[i][jj][q] + bv;
          if (RELU) v = fmaxf(v, 0.f);
          po[(size_t)(off_e + r) * ostr + col] = f2b(v);
        }
      }
    }
  }
}

// ---------- combine (blocks 0..2047) + loss1 rider (blocks 2048..2079) ----------
__global__ __launch_bounds__(256) void combine_kernel(const u16* __restrict__ pb,
                                                      const float* __restrict__ b2,
                                                      const int4* __restrict__ rowinfo,
                                                      const int* __restrict__ slot_of,
                                                      const float* __restrict__ loadrow,
                                                      float* __restrict__ y,
                                                      float* __restrict__ partials){
  if (blockIdx.x >= 2048){
    // ---- loss1 path ----
    __shared__ float part[16][256];
    int tid = threadIdx.x;
    int r = (blockIdx.x - 2048) * 256 + tid;
    int4 ri = rowinfo[r];
    float g0 = __int_as_float(ri.z), g1 = __int_as_float(ri.w);
    f32x4 l0 = *(const f32x4*)&loadrow[r * 8];
    f32x4 l1 = *(const f32x4*)&loadrow[r * 8 + 4];
    #pragma unroll
    for (int e = 0; e < 8; e++){
      part[e][tid] = ((ri.x == e) ? g0 : 0.f) + ((ri.y == e) ? g1 : 0.f);
      part[8 + e][tid] = (e < 4) ? l0[e & 3] : l1[e & 3];
    }
    __syncthreads();
    #pragma unroll
    for (int s = 128; s >= 1; s >>= 1){
      if (tid < s){
        #pragma unroll
        for (int e = 0; e < 16; e++) part[e][tid] += part[e][tid + s];
      }
      __syncthreads();
    }
    if (tid < 16) partials[(blockIdx.x - 2048) * 16 + tid] = part[tid][0];
    return;
  }
  // ---- combine path: 4 rows/block, wave-per-row, 2 K-partials ----
  const size_t PS = (size_t)16384 * 1024;
  int w = threadIdx.x >> 6, lane = threadIdx.x & 63;
  int row = blockIdx.x * 4 + w;
  int4 ri = rowinfo[row];
  float g0 = __int_as_float(ri.z), g1 = __int_as_float(ri.w);
  int s0 = slot_of[2 * row], s1 = slot_of[2 * row + 1];
  const u16* pa = pb + ((size_t)s0 << 10);
  const u16* pbb = pb + ((size_t)s1 << 10);
  #pragma unroll
  for (int k = 0; k < 4; k++){
    int c4 = k * 256 + lane * 4;
    float4 sum0 = *(const float4*)&b2[(ri.x << 10) + c4];
    float4 sum1 = *(const float4*)&b2[(ri.y << 10) + c4];
    #pragma unroll
    for (int kh = 0; kh < 2; kh++){
      u16x4 a = *(const u16x4*)&pa[kh * PS + c4];
      u16x4 b = *(const u16x4*)&pbb[kh * PS + c4];
      sum0.x += b2f(a.x); sum0.y += b2f(a.y); sum0.z += b2f(a.z); sum0.w += b2f(a.w);
      sum1.x += b2f(b.x); sum1.y += b2f(b.y); sum1.z += b2f(b.z); sum1.w += b2f(b.w);
    }
    float4 o;
    o.x = g0 * sum0.x + g1 * sum1.x;
    o.y = g0 * sum0.y + g1 * sum1.y;
    o.z = g0 * sum0.z + g1 * sum1.z;
    o.w = g0 * sum0.w + g1 * sum1.w;
    *(float4*)&y[(size_t)row * 1024 + c4] = o;
  }
}

// ---------- loss stage 2 ----------
__global__ __launch_bounds__(64) void loss2_kernel(const float* __restrict__ partials,
                                                   float* __restrict__ out_loss){
  __shared__ float tot[16];
  int tid = threadIdx.x;
  if (tid < 16){
    float s = 0.f;
    for (int b = 0; b < 32; b++) s += partials[b * 16 + tid];
    tot[tid] = s;
  }
  __syncthreads();
  if (tid == 0){
    float mi = 0.f, ml = 0.f;
    for (int e = 0; e < 8; e++){ mi += tot[e]; ml += tot[8 + e]; }
    mi *= 0.125f; ml *= 0.125f;
    float vi = 0.f, vl = 0.f;
    for (int e = 0; e < 8; e++){
      float di = tot[e] - mi; vi += di * di;
      float dl = tot[8 + e] - ml; vl += dl * dl;
    }
    vi /= 7.f; vl /= 7.f;
    float cvi = vi / (mi * mi + 1e-10f);
    float cvl = vl / (ml * ml + 1e-10f);
    out_loss[0] = 0.01f * (cvi + cvl);
  }
}

// ---------- launch ----------
extern "C" void kernel_launch(void* const* d_in, const int* in_sizes, int n_in,
                              void* d_out, int out_size, void* d_ws, size_t ws_size,
                              hipStream_t stream){
  const float* x  = (const float*)d_in[0];
  const float* nz = (const float*)d_in[1];
  const float* wg = (const float*)d_in[2];
  const float* wn = (const float*)d_in[3];
  const float* W1 = (const float*)d_in[4];
  const float* b1 = (const float*)d_in[5];
  const float* W2 = (const float*)d_in[6];
  const float* b2 = (const float*)d_in[7];
  float* y = (float*)d_out;
  float* loss = y + (size_t)8192 * 1024;

  char* ws = (char*)d_ws;
  size_t o = 0;
  auto alloc = [&](size_t bytes){ size_t r = o; o += (bytes + 255) & ~(size_t)255; return r; };
  int*  counts  = (int*)(ws + alloc(64));
  int*  cnt2    = (int*)(ws + alloc(64));
  int*  offs    = (int*)(ws + alloc(64));
  int*  btab    = (int*)(ws + alloc(1024));
  int4* rowinfo = (int4*)(ws + alloc((size_t)8192 * 16));
  int*  slot_of = (int*)(ws + alloc((size_t)16384 * 4));
  int*  tok     = (int*)(ws + alloc((size_t)16384 * 4));
  float* loadrow = (float*)(ws + alloc((size_t)8192 * 8 * 4));
  float* partials = (float*)(ws + alloc(32 * 16 * 4));
  u16*  xb      = (u16*)(ws + alloc((size_t)8192 * 1024 * 2));
  u16*  w1t     = (u16*)(ws + alloc((size_t)8 * 1024 * 4096 * 2));
  u16*  w2t     = (u16*)(ws + alloc((size_t)8 * 1024 * 4096 * 2));
  u16*  h_buf   = (u16*)(ws + alloc((size_t)16384 * 4096 * 2));
  u16*  pbuf    = (u16*)(ws + alloc((size_t)2 * 16384 * 1024 * 2));
  if (o > ws_size) return;

  hipMemsetAsync(ws, 0, 768, stream);  // counts, cnt2, offs

  prep_kernel<<<16896, 256, 0, stream>>>(x, nz, wg, wn, W1, W2,
                                         counts, rowinfo, loadrow, xb, w1t, w2t);
  fill_kernel<<<32, 256, 0, stream>>>(counts, rowinfo, offs, cnt2, tok, slot_of, btab);
  // ffn1: K=1024, bf16 out with bias+relu (nc=16 col tiles, kh always 0)
  ffn8_kernel<1024, true, true, false><<<dim3(72, 16), 512, 0, stream>>>(
      xb, w1t, b1, h_buf, counts, offs, btab, tok, 16, 1024, 4096, 0);
  // ffn2: K split 2x2048 (nc=4 col tiles x 2 kh), bf16 partials
  ffn8_kernel<4096, false, false, true><<<dim3(72, 8), 512, 0, stream>>>(
      h_buf, w2t, nullptr, pbuf, counts, offs, btab, tok, 4, 2048, 1024,
      (size_t)16384 * 1024);
  combine_kernel<<<2080, 256, 0, stream>>>(pbuf, b2, rowinfo, slot_of, loadrow, y, partials);
  loss2_kernel<<<1, 64, 0, stream>>>(partials, loss);
}

// Round 12
// 624.747 us; speedup vs baseline: 1.1365x; 1.0119x over previous
//
#include <hip/hip_runtime.h>

typedef unsigned short u16;
typedef unsigned int u32;
typedef __attribute__((ext_vector_type(4))) float f32x4;
typedef __attribute__((ext_vector_type(8))) short short8;
typedef __attribute__((ext_vector_type(4))) unsigned short u16x4;

#define BARR __builtin_amdgcn_s_barrier()
#define VM4  asm volatile("s_waitcnt vmcnt(4)" ::: "memory")
#define VM0  asm volatile("s_waitcnt vmcnt(0)" ::: "memory")

// ---------- helpers ----------
__device__ __forceinline__ u16 f2b(float f){
  u32 u = __float_as_uint(f);
  u = (u + 0x7FFFu + ((u >> 16) & 1u)) >> 16;   // RNE
  return (u16)u;
}
__device__ __forceinline__ float b2f(u16 h){ return __uint_as_float(((u32)h) << 16); }

__device__ __forceinline__ void gload16(const void* g, void* l){
  __builtin_amdgcn_global_load_lds((__attribute__((address_space(1))) void*)(g),
                                   (__attribute__((address_space(3))) void*)(l), 16, 0, 0);
}

// ---------- prep: gating (blocks 0..511) + W1/W2 transpose (blocks 512..16895) ----------
__global__ __launch_bounds__(256) void prep_kernel(const float* __restrict__ x,
                                                   const float* __restrict__ nz,
                                                   const float* __restrict__ wg,
                                                   const float* __restrict__ wn,
                                                   const float* __restrict__ W1,
                                                   const float* __restrict__ W2,
                                                   int* __restrict__ counts,
                                                   int4* __restrict__ rowinfo,
                                                   float* __restrict__ loadrow,
                                                   u16* __restrict__ xb,
                                                   u16* __restrict__ w1t,
                                                   u16* __restrict__ w2t){
  __shared__ __align__(16) char SM[17408];
  int b = blockIdx.x;
  int tid = threadIdx.x;
  if (b >= 512){
    int t = b - 512;
    const float* src; u16* dst; int R, C, r0, c0; size_t eo;
    if (t < 8192){                       // W1: [1024][4096] -> w1t [4096][1024]
      src = W1; dst = w1t; R = 1024; C = 4096;
      int e = t >> 10, rem = t & 1023;
      c0 = (rem & 63) * 64; r0 = (rem >> 6) * 64;
      eo = (size_t)R * C * e;
    } else {                             // W2: [4096][1024] -> w2t [1024][4096]
      t -= 8192;
      src = W2; dst = w2t; R = 4096; C = 1024;
      int e = t >> 10, rem = t & 1023;
      r0 = (rem & 63) * 64; c0 = (rem >> 6) * 64;
      eo = (size_t)R * C * e;
    }
    float (*tt)[65] = (float(*)[65])SM;
    int lr = tid >> 4, lc4 = (tid & 15) * 4;
    #pragma unroll
    for (int i = 0; i < 4; i++){
      int r = lr + i * 16;
      float4 v = *(const float4*)&src[eo + (size_t)(r0 + r) * C + c0 + lc4];
      tt[r][lc4] = v.x; tt[r][lc4 + 1] = v.y; tt[r][lc4 + 2] = v.z; tt[r][lc4 + 3] = v.w;
    }
    __syncthreads();
    #pragma unroll
    for (int i = 0; i < 4; i++){
      int c = lr + i * 16;
      u16x4 o = { f2b(tt[lc4][c]), f2b(tt[lc4 + 1][c]), f2b(tt[lc4 + 2][c]), f2b(tt[lc4 + 3][c]) };
      *(u16x4*)&dst[eo + (size_t)(c0 + c) * R + r0 + lc4] = o;
    }
    return;
  }
  // ---- gating path ----
  float (*wpart)[4][17] = (float(*)[4][17])SM;
  int w = tid >> 6, lane = tid & 63;
  int d0 = w * 256 + lane * 4;
  float4 wgA[4], wgB[4], wnA[4], wnB[4];
  #pragma unroll
  for (int k = 0; k < 4; k++){
    wgA[k] = *(const float4*)&wg[(d0 + k) * 8];
    wgB[k] = *(const float4*)&wg[(d0 + k) * 8 + 4];
    wnA[k] = *(const float4*)&wn[(d0 + k) * 8];
    wnB[k] = *(const float4*)&wn[(d0 + k) * 8 + 4];
  }
  int rbase = b * 16;
  for (int r = 0; r < 16; r++){
    int row = rbase + r;
    float4 xv = *(const float4*)&x[(size_t)row * 1024 + d0];
    u16x4 xo = { f2b(xv.x), f2b(xv.y), f2b(xv.z), f2b(xv.w) };
    *(u16x4*)&xb[(size_t)row * 1024 + d0] = xo;
    float ag[8], an[8];
    #pragma unroll
    for (int e = 0; e < 8; e++){ ag[e] = 0.f; an[e] = 0.f; }
    float xk[4] = { xv.x, xv.y, xv.z, xv.w };
    #pragma unroll
    for (int k = 0; k < 4; k++){
      ag[0] = fmaf(xk[k], wgA[k].x, ag[0]); ag[1] = fmaf(xk[k], wgA[k].y, ag[1]);
      ag[2] = fmaf(xk[k], wgA[k].z, ag[2]); ag[3] = fmaf(xk[k], wgA[k].w, ag[3]);
      ag[4] = fmaf(xk[k], wgB[k].x, ag[4]); ag[5] = fmaf(xk[k], wgB[k].y, ag[5]);
      ag[6] = fmaf(xk[k], wgB[k].z, ag[6]); ag[7] = fmaf(xk[k], wgB[k].w, ag[7]);
      an[0] = fmaf(xk[k], wnA[k].x, an[0]); an[1] = fmaf(xk[k], wnA[k].y, an[1]);
      an[2] = fmaf(xk[k], wnA[k].z, an[2]); an[3] = fmaf(xk[k], wnA[k].w, an[3]);
      an[4] = fmaf(xk[k], wnB[k].x, an[4]); an[5] = fmaf(xk[k], wnB[k].y, an[5]);
      an[6] = fmaf(xk[k], wnB[k].z, an[6]); an[7] = fmaf(xk[k], wnB[k].w, an[7]);
    }
    #pragma unroll
    for (int off = 32; off >= 1; off >>= 1){
      #pragma unroll
      for (int e = 0; e < 8; e++){
        ag[e] += __shfl_xor(ag[e], off, 64);
        an[e] += __shfl_xor(an[e], off, 64);
      }
    }
    if (lane == 0){
      #pragma unroll
      for (int e = 0; e < 8; e++){
        wpart[r][w][e] = ag[e];
        wpart[r][w][8 + e] = an[e];
      }
    }
  }
  __syncthreads();
  if (tid < 16){
    int r = tid, row = rbase + r;
    float cg[16];
    #pragma unroll
    for (int v = 0; v < 16; v++)
      cg[v] = wpart[r][0][v] + wpart[r][1][v] + wpart[r][2][v] + wpart[r][3][v];
    float clean[8], sd[8], noisy[8];
    #pragma unroll
    for (int e = 0; e < 8; e++){
      clean[e] = cg[e];
      float v = cg[8 + e];
      float sp = fmaxf(v, 0.f) + log1pf(expf(-fabsf(v)));
      sd[e] = sp + 0.01f;
      noisy[e] = clean[e] + nz[row * 8 + e] * sd[e];
    }
    int i0 = 0, i1 = -1;
    float b0 = -3.4e38f, b1v = -3.4e38f, b2v = -3.4e38f;
    #pragma unroll
    for (int j = 0; j < 8; j++){
      float t = noisy[j];
      if (t > b0){ b2v = b1v; b1v = b0; i1 = i0; b0 = t; i0 = j; }
      else if (t > b1v){ b2v = b1v; b1v = t; i1 = j; }
      else if (t > b2v){ b2v = t; }
    }
    float eg = expf(b1v - b0);
    float g0 = 1.f / (1.f + eg), g1 = eg / (1.f + eg);
    rowinfo[row] = make_int4(i0, i1, __float_as_int(g0), __float_as_int(g1));
    atomicAdd(&counts[i0], 1);
    atomicAdd(&counts[i1], 1);
    float thr_in = b2v, thr_out = b1v;
    #pragma unroll
    for (int e = 0; e < 8; e++){
      bool isin = noisy[e] > thr_in;
      float thr = isin ? thr_in : thr_out;
      float z = (clean[e] - thr) / sd[e];
      loadrow[row * 8 + e] = 0.5f * (1.f + erff(z * 0.70710678118654752f));
    }
  }
}

// ---------- fill dispatch lists + loss1 rider (same 32x256 row coverage) ----------
__global__ __launch_bounds__(256) void fill_kernel(const int* __restrict__ counts,
                                                   const int4* __restrict__ rowinfo,
                                                   const float* __restrict__ loadrow,
                                                   int* __restrict__ offs,
                                                   int* __restrict__ cnt2,
                                                   int* __restrict__ tok,
                                                   int* __restrict__ slot_of,
                                                   int* __restrict__ btab,
                                                   float* __restrict__ partials){
  __shared__ int loff[8];
  __shared__ float part[16][256];
  int tid = threadIdx.x;
  if (tid == 0){
    int s = 0;
    for (int e = 0; e < 8; e++){ loff[e] = s; s += counts[e]; }
    if (blockIdx.x == 0){
      int nb = 0;
      for (int e = 0; e < 8; e++){
        offs[e] = loff[e];
        int nbe = (counts[e] + 255) >> 8;
        for (int t = 0; t < nbe; t++) btab[nb++] = (e << 16) | t;
      }
      offs[15] = nb;
    }
  }
  __syncthreads();
  int r = blockIdx.x * 256 + tid;
  int4 ri = rowinfo[r];
  int p0 = atomicAdd(&cnt2[ri.x], 1);
  int s0 = loff[ri.x] + p0;
  tok[s0] = r; slot_of[2 * r] = s0;
  int p1 = atomicAdd(&cnt2[ri.y], 1);
  int s1 = loff[ri.y] + p1;
  tok[s1] = r; slot_of[2 * r + 1] = s1;
  // loss1 rider
  float g0 = __int_as_float(ri.z), g1 = __int_as_float(ri.w);
  f32x4 l0 = *(const f32x4*)&loadrow[r * 8];
  f32x4 l1 = *(const f32x4*)&loadrow[r * 8 + 4];
  #pragma unroll
  for (int e = 0; e < 8; e++){
    part[e][tid] = ((ri.x == e) ? g0 : 0.f) + ((ri.y == e) ? g1 : 0.f);
    part[8 + e][tid] = (e < 4) ? l0[e & 3] : l1[e & 3];
  }
  __syncthreads();
  #pragma unroll
  for (int s = 128; s >= 1; s >>= 1){
    if (tid < s){
      #pragma unroll
      for (int e = 0; e < 16; e++) part[e][tid] += part[e][tid + s];
    }
    __syncthreads();
  }
  if (tid < 16) partials[blockIdx.x * 16 + tid] = part[tid][0];
}

// ---------- grouped GEMM, 256x256, 8-phase counted-vmcnt, ONE barrier per phase ----
// R12: second barrier of each phase deleted. Hazard proof:
//  WAR: every ds_read issues before its phase's barrier; the next stage into that
//   region issues >=1 barrier later in program order (early-hoisted reads each have
//   an intervening barrier before their region's next stage — checked pairwise).
//  RAW: VM4 moved BEFORE the P4/P8 barrier; gload ledger identical to R8-R11
//   (VM4 position vs stages unchanged): P4's VM4 completes exactly all of t1,
//   P8's completes all of t2. Readers cross that barrier before reading.
template<int KDIM, bool GATHER, bool RELU, bool PSPLIT>
__global__ __launch_bounds__(512, 1) void ffn8_kernel(
    const u16* __restrict__ Ag, const u16* __restrict__ Bt,
    const float* __restrict__ bias, u16* __restrict__ outp,
    const int* __restrict__ counts, const int* __restrict__ offs,
    const int* __restrict__ btab, const int* __restrict__ tok,
    int nc, int klen, int ostr, size_t pstride)
{
  __shared__ u16 As[2][2][128 * 64];
  __shared__ u16 Bs[2][2][128 * 64];

  int gx = gridDim.x;
  int lin = blockIdx.y * gx + blockIdx.x;
  int total = gx * gridDim.y, chunk = total >> 3;
  int swz = (lin & 7) * chunk + (lin >> 3);       // bijective: total % 8 == 0
  int bx = swz % gx, tq = swz / gx;
  int nblk = offs[15];
  if (bx >= nblk) return;
  int kh = tq / nc;
  int tn = tq - kh * nc;
  int kbase = kh * klen;
  int niter = klen >> 7;
  int et = btab[bx]; int e = et >> 16, tm = et & 0xffff;
  int cnt = counts[e], off_e = offs[e];

  int tid = threadIdx.x, lane = tid & 63;
  int wid = tid >> 6, wm = wid >> 2, wn = wid & 3;

  int rl0 = tid >> 3, c8 = tid & 7;
  const char* Abase = (const char*)Ag + (size_t)kbase * 2;
  const char* Bbase = (const char*)(Bt + (size_t)e * 4194304) + (size_t)kbase * 2;
  u32 aoff[4], boff[4];
  #pragma unroll
  for (int h = 0; h < 2; h++)
    #pragma unroll
    for (int r = 0; r < 2; r++){
      int rl = h * 128 + r * 64 + rl0;
      int c8s = c8 ^ (rl & 7);
      int rr = tm * 256 + rl;
      int rc = (rr < cnt) ? rr : (cnt - 1);
      size_t arow = GATHER ? (size_t)tok[off_e + rc] : (size_t)(off_e + rc);
      aoff[h * 2 + r] = (u32)(arow * (KDIM * 2) + c8s * 16);
      boff[h * 2 + r] = (u32)((size_t)(tn * 256 + rl) * (KDIM * 2) + c8s * 16);
    }
  int ldst = (tid & ~63) * 8;

  auto stA = [&](int b, int h, int t){
    const char* s = Abase + (size_t)t * 128;
    gload16(s + aoff[h * 2 + 0], &As[b][h][ldst]);
    gload16(s + aoff[h * 2 + 1], &As[b][h][4096 + ldst]);
  };
  auto stB = [&](int b, int h, int t){
    const char* s = Bbase + (size_t)t * 128;
    gload16(s + boff[h * 2 + 0], &Bs[b][h][ldst]);
    gload16(s + boff[h * 2 + 1], &Bs[b][h][4096 + ldst]);
  };

  int lm = lane & 15, lkb = (lane >> 4) * 8;
  short8 Ar[4][2], Br[2][2][2];
  auto ldA = [&](int b, int rh){
    #pragma unroll
    for (int ii = 0; ii < 4; ii++){
      int rl = rh * 64 + ii * 16 + lm;
      #pragma unroll
      for (int ks = 0; ks < 2; ks++){
        int idx = (rl * 64 + ks * 32 + lkb) ^ ((rl & 7) << 3);
        Ar[ii][ks] = *(const short8*)&As[b][wm][idx];
      }
    }
  };
  auto ldB = [&](int b, int ch){
    #pragma unroll
    for (int jj = 0; jj < 2; jj++){
      int rb = wn * 64 + ch * 32 + jj * 16 + lm;
      int hB = rb >> 7, rl = rb & 127;
      #pragma unroll
      for (int ks = 0; ks < 2; ks++){
        int idx = (rl * 64 + ks * 32 + lkb) ^ ((rl & 7) << 3);
        Br[ch][jj][ks] = *(const short8*)&Bs[b][hB][idx];
      }
    }
  };

  f32x4 acc[8][4];
  #pragma unroll
  for (int i = 0; i < 8; i++)
    #pragma unroll
    for (int j = 0; j < 4; j++) acc[i][j] = (f32x4){0.f, 0.f, 0.f, 0.f};

  auto mfmaQ = [&](int rh, int ch){
    __builtin_amdgcn_s_setprio(1);
    #pragma unroll
    for (int ks = 0; ks < 2; ks++)
      #pragma unroll
      for (int ii = 0; ii < 4; ii++)
        #pragma unroll
        for (int jj = 0; jj < 2; jj++)
          acc[rh * 4 + ii][ch * 2 + jj] = __builtin_amdgcn_mfma_f32_16x16x32_bf16(
              Ar[ii][ks], Br[ch][jj][ks], acc[rh * 4 + ii][ch * 2 + jj], 0, 0, 0);
    __builtin_amdgcn_s_setprio(0);
  };

  // prologue: t0 all 4 halves -> buf0; t1's B-h0, A-h0 -> buf1
  stA(0, 0, 0); stA(0, 1, 0); stB(0, 0, 0); stB(0, 1, 0);
  stB(1, 0, 1); stA(1, 0, 1);
  VM4; BARR;

  for (int j = 0; j < niter - 1; ++j){
    int t1 = 2 * j + 1, t2 = 2 * j + 2, t3 = 2 * j + 3;
    // P1
    ldA(0, 0); ldB(0, 0);
    stA(1, 1, t1);
    BARR; mfmaQ(0, 0); ldB(0, 1);
    // P2
    stB(1, 1, t1);
    BARR; mfmaQ(0, 1); ldA(0, 1);
    // P3
    stB(0, 0, t2);
    BARR; mfmaQ(1, 1);
    // P4
    stA(0, 0, t2);
    VM4; BARR; mfmaQ(1, 0);
    // P5
    ldA(1, 0); ldB(1, 0);
    stA(0, 1, t2);
    BARR; mfmaQ(0, 0); ldB(1, 1);
    // P6
    stB(0, 1, t2);
    BARR; mfmaQ(0, 1); ldA(1, 1);
    // P7
    stB(1, 0, t3);
    BARR; mfmaQ(1, 1);
    // P8
    stA(1, 0, t3);
    VM4; BARR; mfmaQ(1, 0);
  }

  { // peeled last iteration: only P1/P2 stage (complete tile NT-1), VM0 drain at P4
    int t1 = (klen >> 6) - 1;
    ldA(0, 0); ldB(0, 0);
    stA(1, 1, t1);
    BARR; mfmaQ(0, 0); ldB(0, 1);
    stB(1, 1, t1);
    BARR; mfmaQ(0, 1); ldA(0, 1);
    BARR; mfmaQ(1, 1);
    VM0; BARR; mfmaQ(1, 0);
    ldA(1, 0); ldB(1, 0);
    BARR; mfmaQ(0, 0); ldB(1, 1);
    BARR; mfmaQ(0, 1); ldA(1, 1);
    BARR; mfmaQ(1, 1);
    BARR; mfmaQ(1, 0);
  }

  // epilogue: direct C write (R8-proven)
  int lr = (lane >> 4) * 4;
  u16* po = outp + (PSPLIT ? (size_t)kh * pstride : 0);
  #pragma unroll
  for (int i = 0; i < 8; i++){
    int row_l = wm * 128 + i * 16 + lr;
    #pragma unroll
    for (int jj = 0; jj < 4; jj++){
      int col = tn * 256 + wn * 64 + jj * 16 + lm;
      float bv = PSPLIT ? 0.f : bias[e * ostr + col];
      #pragma unroll
      for (int q = 0; q < 4; q++){
        int r = tm * 256 + row_l + q;
        if (r < cnt){
          float v = acc[i][jj][q] + bv;
          if (RELU) v = fmaxf(v, 0.f);
          po[(size_t)(off_e + r) * ostr + col] = f2b(v);
        }
      }
    }
  }
}

// ---------- combine (blocks 0..2047) + loss2 rider (block 2048) ----------
__global__ __launch_bounds__(256) void combine_kernel(const u16* __restrict__ pb,
                                                      const float* __restrict__ b2,
                                                      const int4* __restrict__ rowinfo,
                                                      const int* __restrict__ slot_of,
                                                      const float* __restrict__ partials,
                                                      float* __restrict__ y,
                                                      float* __restrict__ out_loss){
  if (blockIdx.x >= 2048){
    // loss2 rider (partials produced by fill, which completed before ffn1)
    __shared__ float tot[16];
    int tid = threadIdx.x;
    if (tid < 16){
      float s = 0.f;
      for (int b = 0; b < 32; b++) s += partials[b * 16 + tid];
      tot[tid] = s;
    }
    __syncthreads();
    if (tid == 0){
      float mi = 0.f, ml = 0.f;
      for (int e = 0; e < 8; e++){ mi += tot[e]; ml += tot[8 + e]; }
      mi *= 0.125f; ml *= 0.125f;
      float vi = 0.f, vl = 0.f;
      for (int e = 0; e < 8; e++){
        float di = tot[e] - mi; vi += di * di;
        float dl = tot[8 + e] - ml; vl += dl * dl;
      }
      vi /= 7.f; vl /= 7.f;
      float cvi = vi / (mi * mi + 1e-10f);
      float cvl = vl / (ml * ml + 1e-10f);
      out_loss[0] = 0.01f * (cvi + cvl);
    }
    return;
  }
  const size_t PS = (size_t)16384 * 1024;
  int w = threadIdx.x >> 6, lane = threadIdx.x & 63;
  int row = blockIdx.x * 4 + w;
  int4 ri = rowinfo[row];
  float g0 = __int_as_float(ri.z), g1 = __int_as_float(ri.w);
  int s0 = slot_of[2 * row], s1 = slot_of[2 * row + 1];
  const u16* pa = pb + ((size_t)s0 << 10);
  const u16* pbb = pb + ((size_t)s1 << 10);
  #pragma unroll
  for (int k = 0; k < 4; k++){
    int c4 = k * 256 + lane * 4;
    float4 sum0 = *(const float4*)&b2[(ri.x << 10) + c4];
    float4 sum1 = *(const float4*)&b2[(ri.y << 10) + c4];
    #pragma unroll
    for (int kh = 0; kh < 2; kh++){
      u16x4 a = *(const u16x4*)&pa[kh * PS + c4];
      u16x4 b = *(const u16x4*)&pbb[kh * PS + c4];
      sum0.x += b2f(a.x); sum0.y += b2f(a.y); sum0.z += b2f(a.z); sum0.w += b2f(a.w);
      sum1.x += b2f(b.x); sum1.y += b2f(b.y); sum1.z += b2f(b.z); sum1.w += b2f(b.w);
    }
    float4 o;
    o.x = g0 * sum0.x + g1 * sum1.x;
    o.y = g0 * sum0.y + g1 * sum1.y;
    o.z = g0 * sum0.z + g1 * sum1.z;
    o.w = g0 * sum0.w + g1 * sum1.w;
    *(float4*)&y[(size_t)row * 1024 + c4] = o;
  }
}

// ---------- launch ----------
extern "C" void kernel_launch(void* const* d_in, const int* in_sizes, int n_in,
                              void* d_out, int out_size, void* d_ws, size_t ws_size,
                              hipStream_t stream){
  const float* x  = (const float*)d_in[0];
  const float* nz = (const float*)d_in[1];
  const float* wg = (const float*)d_in[2];
  const float* wn = (const float*)d_in[3];
  const float* W1 = (const float*)d_in[4];
  const float* b1 = (const float*)d_in[5];
  const float* W2 = (const float*)d_in[6];
  const float* b2 = (const float*)d_in[7];
  float* y = (float*)d_out;
  float* loss = y + (size_t)8192 * 1024;

  char* ws = (char*)d_ws;
  size_t o = 0;
  auto alloc = [&](size_t bytes){ size_t r = o; o += (bytes + 255) & ~(size_t)255; return r; };
  int*  counts  = (int*)(ws + alloc(64));
  int*  cnt2    = (int*)(ws + alloc(64));
  int*  offs    = (int*)(ws + alloc(64));
  int*  btab    = (int*)(ws + alloc(1024));
  int4* rowinfo = (int4*)(ws + alloc((size_t)8192 * 16));
  int*  slot_of = (int*)(ws + alloc((size_t)16384 * 4));
  int*  tok     = (int*)(ws + alloc((size_t)16384 * 4));
  float* loadrow = (float*)(ws + alloc((size_t)8192 * 8 * 4));
  float* partials = (float*)(ws + alloc(32 * 16 * 4));
  u16*  xb      = (u16*)(ws + alloc((size_t)8192 * 1024 * 2));
  u16*  w1t     = (u16*)(ws + alloc((size_t)8 * 1024 * 4096 * 2));
  u16*  w2t     = (u16*)(ws + alloc((size_t)8 * 1024 * 4096 * 2));
  u16*  h_buf   = (u16*)(ws + alloc((size_t)16384 * 4096 * 2));
  u16*  pbuf    = (u16*)(ws + alloc((size_t)2 * 16384 * 1024 * 2));
  if (o > ws_size) return;

  hipMemsetAsync(ws, 0, 768, stream);  // counts, cnt2, offs

  prep_kernel<<<16896, 256, 0, stream>>>(x, nz, wg, wn, W1, W2,
                                         counts, rowinfo, loadrow, xb, w1t, w2t);
  fill_kernel<<<32, 256, 0, stream>>>(counts, rowinfo, loadrow,
                                      offs, cnt2, tok, slot_of, btab, partials);
  ffn8_kernel<1024, true, true, false><<<dim3(72, 16), 512, 0, stream>>>(
      xb, w1t, b1, h_buf, counts, offs, btab, tok, 16, 1024, 4096, 0);
  ffn8_kernel<4096, false, false, true><<<dim3(72, 8), 512, 0, stream>>>(
      h_buf, w2t, nullptr, pbuf, counts, offs, btab, tok, 4, 2048, 1024,
      (size_t)16384 * 1024);
  combine_kernel<<<2049, 256, 0, stream>>>(pbuf, b2, rowinfo, slot_of, partials, y, loss);
}